// Round 1
// baseline (548.405 us; speedup 1.0000x reference)
//
#include <hip/hip_runtime.h>
#include <math.h>

#define D_MODEL 1024
#define NUM_EXP 64
#define B_SZ 16
#define L_SZ 2048

using bf16x8  = __attribute__((ext_vector_type(8))) __bf16;
using floatx4 = __attribute__((ext_vector_type(4))) float;
using ushort8 = __attribute__((ext_vector_type(8))) unsigned short;
using ushort4v = __attribute__((ext_vector_type(4))) unsigned short;

__device__ __forceinline__ unsigned short f2bf(float f) {
    union { float f; unsigned u; } x; x.f = f;
    unsigned r = (x.u + 0x7fffu + ((x.u >> 16) & 1u)) >> 16;
    return (unsigned short)r;
}
__device__ __forceinline__ float bf2f(unsigned short h) {
    union { unsigned u; float f; } x; x.u = ((unsigned)h) << 16;
    return x.f;
}

// async 16B global->LDS (lds base wave-uniform; lane i lands at base+16*i)
#define GLD16(gp, lp) __builtin_amdgcn_global_load_lds( \
    (const __attribute__((address_space(1))) unsigned int*)(gp), \
    (__attribute__((address_space(3))) unsigned int*)(lp), 16, 0, 0)

// ---------------- x: f32 -> bf16, both [B,L,D] and transposed [B,D,L] ----------------
__global__ void k_convx(const float* __restrict__ in, unsigned short* __restrict__ outN,
                        unsigned short* __restrict__ outT)
{
    __shared__ unsigned short T[64][65];
    const int b = blockIdx.z;
    const int l0 = blockIdx.y * 64, c0 = blockIdx.x * 64;
    const int t = threadIdx.x;
    const int tr = t >> 4, tc = (t & 15) * 4;
    const float* src = in + ((long)b * L_SZ + l0) * D_MODEL + c0;
    unsigned short* dN = outN + ((long)b * L_SZ + l0) * D_MODEL + c0;
    #pragma unroll
    for (int i = 0; i < 4; i++) {
        int r = tr + i * 16;
        float4 v = *(const float4*)(src + (long)r * D_MODEL + tc);
        ushort4v u; u[0]=f2bf(v.x); u[1]=f2bf(v.y); u[2]=f2bf(v.z); u[3]=f2bf(v.w);
        *(ushort4v*)(dN + (long)r * D_MODEL + tc) = u;
        T[r][tc+0]=u[0]; T[r][tc+1]=u[1]; T[r][tc+2]=u[2]; T[r][tc+3]=u[3];
    }
    __syncthreads();
    unsigned short* dT = outT + ((long)b * D_MODEL + c0) * L_SZ + l0;
    #pragma unroll
    for (int i = 0; i < 4; i++) {
        int c = tr + i * 16;
        ushort4v u;
        u[0]=T[tc+0][c]; u[1]=T[tc+1][c]; u[2]=T[tc+2][c]; u[3]=T[tc+3][c];
        *(ushort4v*)(dT + (long)c * L_SZ + tc) = u;
    }
}

// ---------------- Wk: f32 [K,N] -> bf16 transposed [N,K] ----------------
__global__ void k_transw(const float* __restrict__ in, unsigned short* __restrict__ outT)
{
    __shared__ unsigned short T[64][65];
    const int r0 = blockIdx.y * 64, c0 = blockIdx.x * 64;
    const int t = threadIdx.x;
    const int tr = t >> 4, tc = (t & 15) * 4;
    const float* src = in + (long)r0 * D_MODEL + c0;
    #pragma unroll
    for (int i = 0; i < 4; i++) {
        int r = tr + i * 16;
        float4 v = *(const float4*)(src + (long)r * D_MODEL + tc);
        T[r][tc+0]=f2bf(v.x); T[r][tc+1]=f2bf(v.y); T[r][tc+2]=f2bf(v.z); T[r][tc+3]=f2bf(v.w);
    }
    __syncthreads();
    unsigned short* dT = outT + ((long)c0) * D_MODEL + r0;
    #pragma unroll
    for (int i = 0; i < 4; i++) {
        int c = tr + i * 16;
        ushort4v u;
        u[0]=T[tc+0][c]; u[1]=T[tc+1][c]; u[2]=T[tc+2][c]; u[3]=T[tc+3][c];
        *(ushort4v*)(dT + (long)c * D_MODEL + tc) = u;
    }
}

// ---------------- Wa/Wb/Ws straight f32->bf16 (merged) ----------------
__global__ void k_convert3(const float* __restrict__ a, const float* __restrict__ b,
                           const float* __restrict__ c,
                           unsigned short* __restrict__ oa, unsigned short* __restrict__ ob,
                           unsigned short* __restrict__ oc)
{
    long i = ((long)blockIdx.x * 256 + threadIdx.x) * 8;
    int which = (int)(i >> 20);
    long off = i & ((1L << 20) - 1);
    const float* src = which == 0 ? a : which == 1 ? b : c;
    unsigned short* dst = which == 0 ? oa : which == 1 ? ob : oc;
    float4 v0 = *(const float4*)(src + off);
    float4 v1 = *(const float4*)(src + off + 4);
    ushort8 r;
    r[0]=f2bf(v0.x); r[1]=f2bf(v0.y); r[2]=f2bf(v0.z); r[3]=f2bf(v0.w);
    r[4]=f2bf(v1.x); r[5]=f2bf(v1.y); r[6]=f2bf(v1.z); r[7]=f2bf(v1.w);
    *(ushort8*)(dst + off) = r;
}

// ---------------- gather q_emb/b_emb rows; qbk[be] = q_row . bk ----------------
__global__ void k_gather(const int* __restrict__ idx, const float* __restrict__ q_emb,
                         const float* __restrict__ b_emb, const float* __restrict__ bk,
                         unsigned short* __restrict__ qexp, float* __restrict__ bias_exp,
                         float* __restrict__ qbk)
{
    int be = blockIdx.x;
    int row = idx[be];
    int t = threadIdx.x;
    const float* qs = q_emb + (long)row * D_MODEL;
    const float* bsrc = b_emb + (long)row * D_MODEL;
    float4 q4 = *(const float4*)(qs + t * 4);
    float4 k4 = *(const float4*)(bk + t * 4);
    float4 b4 = *(const float4*)(bsrc + t * 4);
    ushort4v r; r[0]=f2bf(q4.x); r[1]=f2bf(q4.y); r[2]=f2bf(q4.z); r[3]=f2bf(q4.w);
    *(ushort4v*)(qexp + (long)be * D_MODEL + t * 4) = r;
    *(float4*)(bias_exp + (long)be * D_MODEL + t * 4) = b4;
    float p = q4.x*k4.x + q4.y*k4.y + q4.z*k4.z + q4.w*k4.w;
    #pragma unroll
    for (int o = 32; o > 0; o >>= 1) p += __shfl_down(p, o);
    __shared__ float red[4];
    if ((t & 63) == 0) red[t >> 6] = p;
    __syncthreads();
    if (t == 0) qbk[be] = red[0] + red[1] + red[2] + red[3];
}

// ---------------- generic bt GEMM: C = epi(A[M,K] @ B[N,K]^T) ----------------
// v = (acc + rowbias[gm]) * scale ; flags: bit0 = bf16 store (else f32)
__launch_bounds__(256)
__global__ void k_gemm_bt(const unsigned short* __restrict__ A,
                          const unsigned short* __restrict__ Bm,
                          const float* __restrict__ rowbias,
                          void* __restrict__ Cout,
                          int M, int N, int K, float scale, int flags,
                          long sA, long sB, long sC)
{
    __shared__ __align__(16) unsigned short As[64 * 32];
    __shared__ __align__(16) unsigned short Bs[64 * 32];
    const int bz = blockIdx.z;
    const unsigned short* Ab = A + (long)bz * sA;
    const unsigned short* Bb = Bm + (long)bz * sB;
    const int tid = threadIdx.x;
    const int wave = tid >> 6, lane = tid & 63;
    const int m0 = blockIdx.y * 64, n0 = blockIdx.x * 64;
    const int lrow = tid >> 2, lk = (tid & 3) * 8;
    const int q = lane >> 4, mr = lane & 15;

    floatx4 acc[4];
    floatx4 z4 = {0.f, 0.f, 0.f, 0.f};
    #pragma unroll
    for (int j = 0; j < 4; j++) acc[j] = z4;

    const unsigned short* Aptr = Ab + (long)(m0 + lrow) * K + lk;
    const unsigned short* Bptr = Bb + (long)(n0 + lrow) * K + lk;

    for (int k0 = 0; k0 < K; k0 += 32) {
        __syncthreads();
        *(ushort8*)&As[lrow * 32 + lk] = *(const ushort8*)(Aptr + k0);
        *(ushort8*)&Bs[lrow * 32 + lk] = *(const ushort8*)(Bptr + k0);
        __syncthreads();
        bf16x8 af = *(const bf16x8*)&As[(wave * 16 + mr) * 32 + q * 8];
        #pragma unroll
        for (int j = 0; j < 4; j++) {
            bf16x8 bfr = *(const bf16x8*)&Bs[(j * 16 + mr) * 32 + q * 8];
            acc[j] = __builtin_amdgcn_mfma_f32_16x16x32_bf16(af, bfr, acc[j], 0, 0, 0);
        }
    }
    #pragma unroll
    for (int j = 0; j < 4; j++) {
        int gn = n0 + j * 16 + mr;
        #pragma unroll
        for (int r = 0; r < 4; r++) {
            int gm = m0 + wave * 16 + q * 4 + r;
            float v = acc[j][r];
            if (rowbias) v += rowbias[(long)bz * M + gm];
            v *= scale;
            long cidx = (long)bz * sC + (long)gm * N + gn;
            if (flags & 1) ((unsigned short*)Cout)[cidx] = f2bf(v);
            else           ((float*)Cout)[cidx] = v;
        }
    }
}

// ---------------- fused fwx GEMM (bt): C1=A1@Bt^T, C2=A2@Bt^T, shared B ----------------
__launch_bounds__(256)
__global__ void k_gemm_fw2(const unsigned short* __restrict__ A1,   // a_fw [B,64,L]
                           const unsigned short* __restrict__ A2,   // b_fw
                           const unsigned short* __restrict__ Bt,   // x_bfT [B,D,L]
                           unsigned short* __restrict__ C1,         // fwx_a [B,64,D]
                           unsigned short* __restrict__ C2)
{
    __shared__ __align__(16) unsigned short As1[64 * 32];
    __shared__ __align__(16) unsigned short As2[64 * 32];
    __shared__ __align__(16) unsigned short Bs[64 * 32];
    const int bz = blockIdx.z;
    const int n0 = blockIdx.x * 64;
    const int tid = threadIdx.x;
    const int wave = tid >> 6, lane = tid & 63;
    const int lrow = tid >> 2, lk = (tid & 3) * 8;
    const int q = lane >> 4, mr = lane & 15;

    const unsigned short* a1p = A1 + ((long)bz * NUM_EXP + lrow) * L_SZ + lk;
    const unsigned short* a2p = A2 + ((long)bz * NUM_EXP + lrow) * L_SZ + lk;
    const unsigned short* bp  = Bt + ((long)bz * D_MODEL + n0 + lrow) * L_SZ + lk;

    floatx4 acc1[4], acc2[4];
    floatx4 z4 = {0.f, 0.f, 0.f, 0.f};
    #pragma unroll
    for (int j = 0; j < 4; j++) { acc1[j] = z4; acc2[j] = z4; }

    for (int k0 = 0; k0 < L_SZ; k0 += 32) {
        __syncthreads();
        *(ushort8*)&As1[lrow * 32 + lk] = *(const ushort8*)(a1p + k0);
        *(ushort8*)&As2[lrow * 32 + lk] = *(const ushort8*)(a2p + k0);
        *(ushort8*)&Bs[lrow * 32 + lk]  = *(const ushort8*)(bp + k0);
        __syncthreads();
        bf16x8 f1 = *(const bf16x8*)&As1[(wave * 16 + mr) * 32 + q * 8];
        bf16x8 f2 = *(const bf16x8*)&As2[(wave * 16 + mr) * 32 + q * 8];
        #pragma unroll
        for (int j = 0; j < 4; j++) {
            bf16x8 bb = *(const bf16x8*)&Bs[(j * 16 + mr) * 32 + q * 8];
            acc1[j] = __builtin_amdgcn_mfma_f32_16x16x32_bf16(f1, bb, acc1[j], 0, 0, 0);
            acc2[j] = __builtin_amdgcn_mfma_f32_16x16x32_bf16(f2, bb, acc2[j], 0, 0, 0);
        }
    }
    #pragma unroll
    for (int j = 0; j < 4; j++) {
        int gn = n0 + j * 16 + mr;
        #pragma unroll
        for (int r = 0; r < 4; r++) {
            int gm = wave * 16 + q * 4 + r;
            long cidx = ((long)bz * NUM_EXP + gm) * D_MODEL + gn;
            C1[cidx] = f2bf(acc1[j][r]);
            C2[cidx] = f2bf(acc2[j][r]);
        }
    }
}

// ---------------- fused cls GEMM (bt): side = blockIdx.z>>4 ----------------
// cls[e,d] = fwx[e,:]·W[d,:] + wsum[e]*bias[d] + biasE[e,d]; split hi/lo, transposed [d,e]
__launch_bounds__(256)
__global__ void k_gemm_cls(const unsigned short* __restrict__ fwxA, const unsigned short* __restrict__ fwxB,
                           const unsigned short* __restrict__ Wa_, const unsigned short* __restrict__ Wb_,
                           const float* __restrict__ ba_, const float* __restrict__ bb_,
                           const float* __restrict__ wsA, const float* __restrict__ wsB,
                           const float* __restrict__ biasE,
                           unsigned short* __restrict__ aHi, unsigned short* __restrict__ aLo,
                           unsigned short* __restrict__ bHi, unsigned short* __restrict__ bLo)
{
    __shared__ __align__(16) unsigned short As[64 * 32];
    __shared__ __align__(16) unsigned short Bs[64 * 32];
    const int zz = blockIdx.z;
    const int side = zz >> 4, bz = zz & 15;
    const unsigned short* Ab = (side ? fwxB : fwxA) + (long)bz * NUM_EXP * D_MODEL;
    const unsigned short* Bb = side ? Wb_ : Wa_;
    const float* cb = side ? bb_ : ba_;
    const float* rw = (side ? wsB : wsA) + bz * NUM_EXP;
    const float* bE = biasE + (long)bz * NUM_EXP * D_MODEL;
    unsigned short* oHi = (side ? bHi : aHi) + (long)bz * NUM_EXP * D_MODEL;
    unsigned short* oLo = (side ? bLo : aLo) + (long)bz * NUM_EXP * D_MODEL;

    const int tid = threadIdx.x;
    const int wave = tid >> 6, lane = tid & 63;
    const int n0 = blockIdx.x * 64;
    const int lrow = tid >> 2, lk = (tid & 3) * 8;
    const int q = lane >> 4, mr = lane & 15;

    floatx4 acc[4];
    floatx4 z4 = {0.f, 0.f, 0.f, 0.f};
    #pragma unroll
    for (int j = 0; j < 4; j++) acc[j] = z4;

    const unsigned short* Aptr = Ab + (long)lrow * D_MODEL + lk;
    const unsigned short* Bptr = Bb + (long)(n0 + lrow) * D_MODEL + lk;

    for (int k0 = 0; k0 < D_MODEL; k0 += 32) {
        __syncthreads();
        *(ushort8*)&As[lrow * 32 + lk] = *(const ushort8*)(Aptr + k0);
        *(ushort8*)&Bs[lrow * 32 + lk] = *(const ushort8*)(Bptr + k0);
        __syncthreads();
        bf16x8 af = *(const bf16x8*)&As[(wave * 16 + mr) * 32 + q * 8];
        #pragma unroll
        for (int j = 0; j < 4; j++) {
            bf16x8 bfr = *(const bf16x8*)&Bs[(j * 16 + mr) * 32 + q * 8];
            acc[j] = __builtin_amdgcn_mfma_f32_16x16x32_bf16(af, bfr, acc[j], 0, 0, 0);
        }
    }
    #pragma unroll
    for (int j = 0; j < 4; j++) {
        int gn = n0 + j * 16 + mr;          // d
        float cbv = cb[gn];
        #pragma unroll
        for (int r = 0; r < 4; r++) {
            int gm = wave * 16 + q * 4 + r; // e
            float v = acc[j][r] + rw[gm] * cbv + bE[(long)gm * D_MODEL + gn];
            unsigned short hi = f2bf(v);
            long tix = (long)gn * NUM_EXP + gm;
            oHi[tix] = hi;
            oLo[tix] = f2bf(v - bf2f(hi));
        }
    }
}

// ---------------- selector GEMM: 256x256 tile, 8-wave, 4-phase/K-tile pipelined ----------------
// T2 (XOR-swizzled LDS via pre-swizzled global src + swizzled read), T3+T4 (phase
// interleave with counted vmcnt across raw s_barriers), T5 (setprio around MFMA).
// Schedule invariants (hand-verified):
//   stage stream leads consumption by 6 half-tiles (12 loads/thread in flight max);
//   vmcnt(8) checkpoints at phases p=1,3 guarantee the 2 half-tiles read by the next
//   phase-pair have landed; every region's re-stage issue point is after the end-barrier
//   of the phase whose lgkmcnt(0) consumed it. Tail stages clamp to tile 15 (dead data,
//   race-free); vmcnt(0) after the loop drains DMA before LDS reassignment.
__launch_bounds__(512, 2)
__global__ void k_gemm_sel(const unsigned short* __restrict__ A,
                           const unsigned short* __restrict__ Bm,
                           const float* __restrict__ bias,
                           unsigned short* __restrict__ C)
{
    // [buf][khalf][256 rows][4 groups x 8 shorts], groups XOR-permuted per row-pair
    __shared__ __align__(16) unsigned short As[2][2][8192];
    __shared__ __align__(16) unsigned short Bs[2][2][8192];

    const int tid = threadIdx.x;
    const int wid = tid >> 6, lane = tid & 63;
    const int q = lane >> 4, mr = lane & 15;
    const int wm = wid >> 2, wn = wid & 3;           // 2x4 wave grid, 128x64 per wave
    const int kread = (q ^ ((mr >> 1) & 3)) * 8;

    // XCD-aware bijective swizzle: 512 blocks = 8 XCDs x 64; each XCD owns 16 m-panels
    const int bid = blockIdx.x;
    const int wg = (bid & 7) * 64 + (bid >> 3);
    const int m0 = (wg >> 2) * 256;
    const int n0 = (wg & 3) * 256;

    const unsigned short* Ag = A + (long)m0 * 1024;
    const unsigned short* Bg = Bm + (long)n0 * 1024;

    // staging: slot s = j*512+tid -> row s>>2, phys group s&3 (j=1: row += 128, same key)
    const int srow = tid >> 2;
    const int sgrp = (tid & 3) ^ ((srow >> 1) & 3);
    const long soff = (long)srow * 1024 + sgrp * 8;
    const int ldst = wid * 64 * 8;                   // wave base (shorts) within region

    auto STAGE = [&](int g) {
        int tile = g >> 2; if (tile > 15) tile = 15; // tail overrun: redundant re-stage
        const int kh = (g >> 1) & 1, isB = g & 1;
        const unsigned short* src = (isB ? Bg : Ag) + (long)tile * 64 + kh * 32 + soff;
        unsigned short* dst = (isB ? &Bs[0][0][0] : &As[0][0][0])
                              + ((tile & 1) * 2 + kh) * 8192 + ldst;
        GLD16(src, dst);
        GLD16(src + 128 * 1024, dst + 4096);
    };

    floatx4 acc[8][4];
    floatx4 z4 = {0.f, 0.f, 0.f, 0.f};
    #pragma unroll
    for (int i = 0; i < 8; i++)
        #pragma unroll
        for (int j = 0; j < 4; j++) acc[i][j] = z4;

    // prologue: tile0 fully + tile1 K-half0 (6 halves = 12 loads/thread)
    STAGE(0); STAGE(1); STAGE(2); STAGE(3); STAGE(4); STAGE(5);
    asm volatile("s_waitcnt vmcnt(4)" ::: "memory");   // tile0's 4 halves landed
    __builtin_amdgcn_s_barrier();

    for (int t = 0; t < 16; t++) {
        const unsigned short* Abuf = &As[t & 1][0][0];
        const unsigned short* Bbuf = &Bs[t & 1][0][0];
        bf16x8 bfr[4];
        #pragma unroll
        for (int p = 0; p < 4; p++) {
            const int kh = p >> 1, mh = p & 1;
            bf16x8 af[4];
            #pragma unroll
            for (int i = 0; i < 4; i++)
                af[i] = *(const bf16x8*)&Abuf[kh * 8192 +
                        (wm * 128 + mh * 64 + i * 16 + mr) * 32 + kread];
            if (mh == 0) {
                #pragma unroll
                for (int j = 0; j < 4; j++)
                    bfr[j] = *(const bf16x8*)&Bbuf[kh * 8192 +
                             (wn * 64 + j * 16 + mr) * 32 + kread];
            }
            STAGE(4 * t + p + 6);
            if (mh == 1) asm volatile("s_waitcnt vmcnt(8)" ::: "memory");
            __builtin_amdgcn_s_barrier();
            asm volatile("s_waitcnt lgkmcnt(0)" ::: "memory");
            __builtin_amdgcn_sched_barrier(0);
            __builtin_amdgcn_s_setprio(1);
            #pragma unroll
            for (int i = 0; i < 4; i++)
                #pragma unroll
                for (int j = 0; j < 4; j++)
                    acc[mh * 4 + i][j] = __builtin_amdgcn_mfma_f32_16x16x32_bf16(
                        af[i], bfr[j], acc[mh * 4 + i][j], 0, 0, 0);
            __builtin_amdgcn_s_setprio(0);
            __builtin_amdgcn_s_barrier();
            __builtin_amdgcn_sched_barrier(0);
        }
    }
    asm volatile("s_waitcnt vmcnt(0)" ::: "memory");   // drain tail DMA before LDS release

    #pragma unroll
    for (int i = 0; i < 8; i++) {
        #pragma unroll
        for (int j = 0; j < 4; j++) {
            const int gn = n0 + wn * 64 + j * 16 + mr;
            const float cbv = bias[gn];
            #pragma unroll
            for (int r = 0; r < 4; r++) {
                const int gm = m0 + wm * 128 + i * 16 + q * 4 + r;
                C[(long)gm * 1024 + gn] = f2bf(acc[i][j][r] + cbv);
            }
        }
    }
}

// ---------------- forward norm over L (masked); wsum = S/(S+eps) ----------------
__global__ void k_fwnorm(const float* __restrict__ z, const int* __restrict__ mask,
                         unsigned short* __restrict__ a_fw, unsigned short* __restrict__ b_fw,
                         float* __restrict__ wsum_a, float* __restrict__ wsum_b)
{
    int be = blockIdx.x;
    int b = be >> 6;
    const float* zr = z + (long)be * L_SZ;
    const int* mr = mask + (long)b * L_SZ;
    int tid = threadIdx.x;
    float sa = 0.f, sb = 0.f;
    for (int l = tid; l < L_SZ; l += 256) {
        float v = zr[l];
        if (mr[l] != 0) { sa += fmaxf(v, 0.f); sb += fmaxf(-v, 0.f); }
    }
    #pragma unroll
    for (int o = 32; o > 0; o >>= 1) { sa += __shfl_down(sa, o); sb += __shfl_down(sb, o); }
    __shared__ float red[8];
    int wave = tid >> 6, lane = tid & 63;
    if (lane == 0) { red[wave] = sa; red[4 + wave] = sb; }
    __syncthreads();
    float ta = red[0] + red[1] + red[2] + red[3];
    float tb = red[4] + red[5] + red[6] + red[7];
    float ia = 1.f / (ta + 1e-9f), ib = 1.f / (tb + 1e-9f);
    if (tid == 0) { wsum_a[be] = ta * ia; wsum_b[be] = tb * ib; }
    for (int l = tid; l < L_SZ; l += 256) {
        float v = zr[l];
        float m = (mr[l] != 0) ? 1.f : 0.f;
        a_fw[(long)be * L_SZ + l] = f2bf(fmaxf(v, 0.f) * m * ia);
        b_fw[(long)be * L_SZ + l] = f2bf(fmaxf(-v, 0.f) * m * ib);
    }
}

// ---------------- backward norm over E (unmasked), bf16 out ----------------
__global__ void k_bwnorm(const float* __restrict__ z, unsigned short* __restrict__ a_bw,
                         unsigned short* __restrict__ b_bw)
{
    int r = blockIdx.x * 256 + threadIdx.x;
    int b = r >> 11, l = r & 2047;
    const float* zb = z + (long)b * NUM_EXP * L_SZ + l;
    float sa = 0.f, sb = 0.f;
    float va[NUM_EXP];
    #pragma unroll 8
    for (int e = 0; e < NUM_EXP; e++) {
        float v = zb[(long)e * L_SZ];
        va[e] = v;
        sa += fmaxf(v, 0.f); sb += fmaxf(-v, 0.f);
    }
    float ia = 1.f / (sa + 1e-9f), ib = 1.f / (sb + 1e-9f);
    unsigned short* ar = a_bw + (long)r * NUM_EXP;
    unsigned short* br = b_bw + (long)r * NUM_EXP;
    #pragma unroll 8
    for (int e = 0; e < NUM_EXP; e++) {
        float v = va[e];
        ar[e] = f2bf(fmaxf(v, 0.f) * ia);
        br[e] = f2bf(fmaxf(-v, 0.f) * ib);
    }
}

// ---------------- final: out = sig(sel)*(aw@clsA) + (1-sig)*(bw@clsB) via MFMA ----------------
__launch_bounds__(256)
__global__ void k_final_mfma(const unsigned short* __restrict__ aw,
                             const unsigned short* __restrict__ bw,
                             const unsigned short* __restrict__ caHi,
                             const unsigned short* __restrict__ caLo,
                             const unsigned short* __restrict__ cbHi,
                             const unsigned short* __restrict__ cbLo,
                             const unsigned short* __restrict__ selbf,   // bf16 logits
                             float* __restrict__ out)
{
    __shared__ __align__(16) unsigned short Aa[64 * 72];
    __shared__ __align__(16) unsigned short Ab[64 * 72];
    __shared__ __align__(16) unsigned short BaH[64 * 72];
    __shared__ __align__(16) unsigned short BaL[64 * 72];
    __shared__ __align__(16) unsigned short BbH[64 * 72];
    __shared__ __align__(16) unsigned short BbL[64 * 72];
    const int bz = blockIdx.z;
    const int l0 = blockIdx.y * 64, d0 = blockIdx.x * 64;
    const int tid = threadIdx.x;
    const int wave = tid >> 6, lane = tid & 63;
    const int q = lane >> 4, mr = lane & 15;

    const unsigned short* awb = aw + ((long)bz * L_SZ + l0) * NUM_EXP;
    const unsigned short* bwb = bw + ((long)bz * L_SZ + l0) * NUM_EXP;
    const long cbase = ((long)bz * D_MODEL + d0) * NUM_EXP;

    #pragma unroll
    for (int c = 0; c < 2; c++) {
        int idx = c * 256 + tid;
        int row = idx >> 3, kc = (idx & 7) * 8;
        int lw = row * 72 + kc;
        long ga = (long)row * NUM_EXP + kc;
        *(ushort8*)&Aa[lw]  = *(const ushort8*)(awb + ga);
        *(ushort8*)&Ab[lw]  = *(const ushort8*)(bwb + ga);
        *(ushort8*)&BaH[lw] = *(const ushort8*)(caHi + cbase + ga);
        *(ushort8*)&BaL[lw] = *(const ushort8*)(caLo + cbase + ga);
        *(ushort8*)&BbH[lw] = *(const ushort8*)(cbHi + cbase + ga);
        *(ushort8*)&BbL[lw] = *(const ushort8*)(cbLo + cbase + ga);
    }
    __syncthreads();

    floatx4 accA[4], accB[4];
    floatx4 z4 = {0.f, 0.f, 0.f, 0.f};
    #pragma unroll
    for (int j = 0; j < 4; j++) { accA[j] = z4; accB[j] = z4; }

    #pragma unroll
    for (int ks = 0; ks < 2; ks++) {
        int ko = ks * 32 + q * 8;
        bf16x8 fa = *(const bf16x8*)&Aa[(wave * 16 + mr) * 72 + ko];
        bf16x8 fb = *(const bf16x8*)&Ab[(wave * 16 + mr) * 72 + ko];
        #pragma unroll
        for (int j = 0; j < 4; j++) {
            int bo = (j * 16 + mr) * 72 + ko;
            accA[j] = __builtin_amdgcn_mfma_f32_16x16x32_bf16(fa, *(const bf16x8*)&BaH[bo], accA[j], 0, 0, 0);
            accA[j] = __builtin_amdgcn_mfma_f32_16x16x32_bf16(fa, *(const bf16x8*)&BaL[bo], accA[j], 0, 0, 0);
            accB[j] = __builtin_amdgcn_mfma_f32_16x16x32_bf16(fb, *(const bf16x8*)&BbH[bo], accB[j], 0, 0, 0);
            accB[j] = __builtin_amdgcn_mfma_f32_16x16x32_bf16(fb, *(const bf16x8*)&BbL[bo], accB[j], 0, 0, 0);
        }
    }

    #pragma unroll
    for (int j = 0; j < 4; j++) {
        #pragma unroll
        for (int r = 0; r < 4; r++) {
            int gl = l0 + wave * 16 + q * 4 + r;
            int gd = d0 + j * 16 + mr;
            long o = ((long)bz * L_SZ + gl) * D_MODEL + gd;
            float s = 1.f / (1.f + __expf(-bf2f(selbf[o])));
            out[o] = s * accA[j][r] + (1.f - s) * accB[j][r];
        }
    }
}

extern "C" void kernel_launch(void* const* d_in, const int* in_sizes, int n_in,
                              void* d_out, int out_size, void* d_ws, size_t ws_size,
                              hipStream_t stream)
{
    const float* x     = (const float*)d_in[0];
    const int*   nidx  = (const int*)d_in[1];
    const int*   mask  = (const int*)d_in[2];
    const float* q_emb = (const float*)d_in[3];
    const float* b_emb = (const float*)d_in[4];
    const float* Wk    = (const float*)d_in[5];
    const float* bk    = (const float*)d_in[6];
    const float* Wa    = (const float*)d_in[7];
    const float* ba    = (const float*)d_in[8];
    const float* Wb    = (const float*)d_in[9];
    const float* bb    = (const float*)d_in[10];
    const float* Ws    = (const float*)d_in[11];
    const float* bs    = (const float*)d_in[12];
    float* out = (float*)d_out;

    constexpr long BLD = (long)B_SZ * L_SZ * D_MODEL;
    constexpr long BEL = (long)B_SZ * NUM_EXP * L_SZ;
    constexpr long BED = (long)B_SZ * NUM_EXP * D_MODEL;
    constexpr long DD  = (long)D_MODEL * D_MODEL;

    char* w = (char*)d_ws;
    size_t off = 0;
    auto carve = [&](size_t bytes) { char* p = w + off; off += (bytes + 255) & ~(size_t)255; return p; };
    unsigned short* x_bf   = (unsigned short*)carve(BLD * 2);
    unsigned short* x_bfT  = (unsigned short*)carve(BLD * 2);  // later reused as sel logits
    unsigned short* wkT_bf = (unsigned short*)carve(DD * 2);
    unsigned short* wa_bf  = (unsigned short*)carve(DD * 2);
    unsigned short* wb_bf  = (unsigned short*)carve(DD * 2);
    unsigned short* ws_bf  = (unsigned short*)carve(DD * 2);
    unsigned short* qexp   = (unsigned short*)carve(BED * 2);
    float*          bias_e = (float*)carve(BED * 4);
    float*          qbk    = (float*)carve(B_SZ * NUM_EXP * 4);
    unsigned short* qk     = (unsigned short*)carve(BED * 2);
    float*          z      = (float*)carve(BEL * 4);
    unsigned short* a_fw   = (unsigned short*)carve(BEL * 2);
    unsigned short* b_fw   = (unsigned short*)carve(BEL * 2);
    float*          wsum_a = (float*)carve(B_SZ * NUM_EXP * 4);
    float*          wsum_b = (float*)carve(B_SZ * NUM_EXP * 4);
    unsigned short* a_bw   = (unsigned short*)carve(BEL * 2);
    unsigned short* b_bw   = (unsigned short*)carve(BEL * 2);
    unsigned short* fwx_a  = (unsigned short*)carve(BED * 2);
    unsigned short* fwx_b  = (unsigned short*)carve(BED * 2);
    unsigned short* caHi   = (unsigned short*)carve(BED * 2);
    unsigned short* caLo   = (unsigned short*)carve(BED * 2);
    unsigned short* cbHi   = (unsigned short*)carve(BED * 2);
    unsigned short* cbLo   = (unsigned short*)carve(BED * 2);
    if (ws_size < off) return;
    unsigned short* selbf = x_bfT;  // x_bfT dead after fw2 GEMM; sel GEMM runs after it

    // 1. conversions / transposes
    k_convx<<<dim3(16, 32, B_SZ), 256, 0, stream>>>(x, x_bf, x_bfT);
    k_transw<<<dim3(16, 16), 256, 0, stream>>>(Wk, wkT_bf);
    k_convert3<<<(3 * DD) / 2048, 256, 0, stream>>>(Wa, Wb, Ws, wa_bf, wb_bf, ws_bf);
    k_gather<<<B_SZ * NUM_EXP, 256, 0, stream>>>(nidx, q_emb, b_emb, bk, qexp, bias_e, qbk);

    // 2. qk[e,n] = sum_d qexp[e,d] * WkT[n,d]   (bf16 out)
    k_gemm_bt<<<dim3(16, 1, B_SZ), 256, 0, stream>>>(qexp, wkT_bf, nullptr, qk,
        NUM_EXP, D_MODEL, D_MODEL, 1.f, 1, (long)NUM_EXP * D_MODEL, 0, (long)NUM_EXP * D_MODEL);

    // 3. z[e,l] = (qk[e,:]·x[l,:] + qbk[e]) / 32  (f32)
    k_gemm_bt<<<dim3(32, 1, B_SZ), 256, 0, stream>>>(qk, x_bf, qbk, z,
        NUM_EXP, L_SZ, D_MODEL, 1.f / 32.f, 0,
        (long)NUM_EXP * D_MODEL, (long)L_SZ * D_MODEL, (long)NUM_EXP * L_SZ);

    // 4. normalizations
    k_fwnorm<<<B_SZ * NUM_EXP, 256, 0, stream>>>(z, mask, a_fw, b_fw, wsum_a, wsum_b);
    k_bwnorm<<<(B_SZ * L_SZ) / 256, 256, 0, stream>>>(z, a_bw, b_bw);

    // 5. fwx_{a,b}[e,c] = sum_l fw[e,l]·xT[c,l]  (fused, shared B)
    k_gemm_fw2<<<dim3(16, 1, B_SZ), 256, 0, stream>>>(a_fw, b_fw, x_bfT, fwx_a, fwx_b);

    // 6. sel logits -> selbf (aliases x_bfT; runs AFTER fw2). 512 blocks = 128m x 4n.
    k_gemm_sel<<<512, 512, 0, stream>>>(x_bf, ws_bf, bs, selbf);

    // 7. cls (both sides fused), transposed split store
    k_gemm_cls<<<dim3(16, 1, 32), 256, 0, stream>>>(fwx_a, fwx_b, wa_bf, wb_bf, ba, bb,
        wsum_a, wsum_b, bias_e, caHi, caLo, cbHi, cbLo);

    // 8. final blend
    k_final_mfma<<<dim3(16, 32, B_SZ), 256, 0, stream>>>(a_bw, b_bw, caHi, caLo, cbHi, cbLo, selbf, out);
}

// Round 2
// 546.208 us; speedup vs baseline: 1.0040x; 1.0040x over previous
//
#include <hip/hip_runtime.h>
#include <math.h>

#define D_MODEL 1024
#define NUM_EXP 64
#define B_SZ 16
#define L_SZ 2048

using bf16x8  = __attribute__((ext_vector_type(8))) __bf16;
using floatx4 = __attribute__((ext_vector_type(4))) float;
using ushort8 = __attribute__((ext_vector_type(8))) unsigned short;
using ushort4v = __attribute__((ext_vector_type(4))) unsigned short;

__device__ __forceinline__ unsigned short f2bf(float f) {
    union { float f; unsigned u; } x; x.f = f;
    unsigned r = (x.u + 0x7fffu + ((x.u >> 16) & 1u)) >> 16;
    return (unsigned short)r;
}
__device__ __forceinline__ float bf2f(unsigned short h) {
    union { unsigned u; float f; } x; x.u = ((unsigned)h) << 16;
    return x.f;
}

// async 16B global->LDS (lds base wave-uniform; lane i lands at base+16*i)
#define GLD16(gp, lp) __builtin_amdgcn_global_load_lds( \
    (const __attribute__((address_space(1))) unsigned int*)(gp), \
    (__attribute__((address_space(3))) unsigned int*)(lp), 16, 0, 0)

// ---------------- x: f32 -> bf16, both [B,L,D] and transposed [B,D,L] ----------------
__global__ void k_convx(const float* __restrict__ in, unsigned short* __restrict__ outN,
                        unsigned short* __restrict__ outT)
{
    __shared__ unsigned short T[64][65];
    const int b = blockIdx.z;
    const int l0 = blockIdx.y * 64, c0 = blockIdx.x * 64;
    const int t = threadIdx.x;
    const int tr = t >> 4, tc = (t & 15) * 4;
    const float* src = in + ((long)b * L_SZ + l0) * D_MODEL + c0;
    unsigned short* dN = outN + ((long)b * L_SZ + l0) * D_MODEL + c0;
    #pragma unroll
    for (int i = 0; i < 4; i++) {
        int r = tr + i * 16;
        float4 v = *(const float4*)(src + (long)r * D_MODEL + tc);
        ushort4v u; u[0]=f2bf(v.x); u[1]=f2bf(v.y); u[2]=f2bf(v.z); u[3]=f2bf(v.w);
        *(ushort4v*)(dN + (long)r * D_MODEL + tc) = u;
        T[r][tc+0]=u[0]; T[r][tc+1]=u[1]; T[r][tc+2]=u[2]; T[r][tc+3]=u[3];
    }
    __syncthreads();
    unsigned short* dT = outT + ((long)b * D_MODEL + c0) * L_SZ + l0;
    #pragma unroll
    for (int i = 0; i < 4; i++) {
        int c = tr + i * 16;
        ushort4v u;
        u[0]=T[tc+0][c]; u[1]=T[tc+1][c]; u[2]=T[tc+2][c]; u[3]=T[tc+3][c];
        *(ushort4v*)(dT + (long)c * L_SZ + tc) = u;
    }
}

// ---------------- Wk: f32 [K,N] -> bf16 transposed [N,K] ----------------
__global__ void k_transw(const float* __restrict__ in, unsigned short* __restrict__ outT)
{
    __shared__ unsigned short T[64][65];
    const int r0 = blockIdx.y * 64, c0 = blockIdx.x * 64;
    const int t = threadIdx.x;
    const int tr = t >> 4, tc = (t & 15) * 4;
    const float* src = in + (long)r0 * D_MODEL + c0;
    #pragma unroll
    for (int i = 0; i < 4; i++) {
        int r = tr + i * 16;
        float4 v = *(const float4*)(src + (long)r * D_MODEL + tc);
        T[r][tc+0]=f2bf(v.x); T[r][tc+1]=f2bf(v.y); T[r][tc+2]=f2bf(v.z); T[r][tc+3]=f2bf(v.w);
    }
    __syncthreads();
    unsigned short* dT = outT + ((long)c0) * D_MODEL + r0;
    #pragma unroll
    for (int i = 0; i < 4; i++) {
        int c = tr + i * 16;
        ushort4v u;
        u[0]=T[tc+0][c]; u[1]=T[tc+1][c]; u[2]=T[tc+2][c]; u[3]=T[tc+3][c];
        *(ushort4v*)(dT + (long)c * D_MODEL + tc) = u;
    }
}

// ---------------- Wa/Wb/Ws straight f32->bf16 (merged) ----------------
__global__ void k_convert3(const float* __restrict__ a, const float* __restrict__ b,
                           const float* __restrict__ c,
                           unsigned short* __restrict__ oa, unsigned short* __restrict__ ob,
                           unsigned short* __restrict__ oc)
{
    long i = ((long)blockIdx.x * 256 + threadIdx.x) * 8;
    int which = (int)(i >> 20);
    long off = i & ((1L << 20) - 1);
    const float* src = which == 0 ? a : which == 1 ? b : c;
    unsigned short* dst = which == 0 ? oa : which == 1 ? ob : oc;
    float4 v0 = *(const float4*)(src + off);
    float4 v1 = *(const float4*)(src + off + 4);
    ushort8 r;
    r[0]=f2bf(v0.x); r[1]=f2bf(v0.y); r[2]=f2bf(v0.z); r[3]=f2bf(v0.w);
    r[4]=f2bf(v1.x); r[5]=f2bf(v1.y); r[6]=f2bf(v1.z); r[7]=f2bf(v1.w);
    *(ushort8*)(dst + off) = r;
}

// ---------------- gather q_emb/b_emb rows; qbk[be] = q_row . bk ----------------
__global__ void k_gather(const int* __restrict__ idx, const float* __restrict__ q_emb,
                         const float* __restrict__ b_emb, const float* __restrict__ bk,
                         unsigned short* __restrict__ qexp, float* __restrict__ bias_exp,
                         float* __restrict__ qbk)
{
    int be = blockIdx.x;
    int row = idx[be];
    int t = threadIdx.x;
    const float* qs = q_emb + (long)row * D_MODEL;
    const float* bsrc = b_emb + (long)row * D_MODEL;
    float4 q4 = *(const float4*)(qs + t * 4);
    float4 k4 = *(const float4*)(bk + t * 4);
    float4 b4 = *(const float4*)(bsrc + t * 4);
    ushort4v r; r[0]=f2bf(q4.x); r[1]=f2bf(q4.y); r[2]=f2bf(q4.z); r[3]=f2bf(q4.w);
    *(ushort4v*)(qexp + (long)be * D_MODEL + t * 4) = r;
    *(float4*)(bias_exp + (long)be * D_MODEL + t * 4) = b4;
    float p = q4.x*k4.x + q4.y*k4.y + q4.z*k4.z + q4.w*k4.w;
    #pragma unroll
    for (int o = 32; o > 0; o >>= 1) p += __shfl_down(p, o);
    __shared__ float red[4];
    if ((t & 63) == 0) red[t >> 6] = p;
    __syncthreads();
    if (t == 0) qbk[be] = red[0] + red[1] + red[2] + red[3];
}

// ---------------- generic bt GEMM: C = epi(A[M,K] @ B[N,K]^T) ----------------
// v = (acc + rowbias[gm]) * scale ; flags: bit0 = bf16 store (else f32)
__launch_bounds__(256)
__global__ void k_gemm_bt(const unsigned short* __restrict__ A,
                          const unsigned short* __restrict__ Bm,
                          const float* __restrict__ rowbias,
                          void* __restrict__ Cout,
                          int M, int N, int K, float scale, int flags,
                          long sA, long sB, long sC)
{
    __shared__ __align__(16) unsigned short As[64 * 32];
    __shared__ __align__(16) unsigned short Bs[64 * 32];
    const int bz = blockIdx.z;
    const unsigned short* Ab = A + (long)bz * sA;
    const unsigned short* Bb = Bm + (long)bz * sB;
    const int tid = threadIdx.x;
    const int wave = tid >> 6, lane = tid & 63;
    const int m0 = blockIdx.y * 64, n0 = blockIdx.x * 64;
    const int lrow = tid >> 2, lk = (tid & 3) * 8;
    const int q = lane >> 4, mr = lane & 15;

    floatx4 acc[4];
    floatx4 z4 = {0.f, 0.f, 0.f, 0.f};
    #pragma unroll
    for (int j = 0; j < 4; j++) acc[j] = z4;

    const unsigned short* Aptr = Ab + (long)(m0 + lrow) * K + lk;
    const unsigned short* Bptr = Bb + (long)(n0 + lrow) * K + lk;

    for (int k0 = 0; k0 < K; k0 += 32) {
        __syncthreads();
        *(ushort8*)&As[lrow * 32 + lk] = *(const ushort8*)(Aptr + k0);
        *(ushort8*)&Bs[lrow * 32 + lk] = *(const ushort8*)(Bptr + k0);
        __syncthreads();
        bf16x8 af = *(const bf16x8*)&As[(wave * 16 + mr) * 32 + q * 8];
        #pragma unroll
        for (int j = 0; j < 4; j++) {
            bf16x8 bfr = *(const bf16x8*)&Bs[(j * 16 + mr) * 32 + q * 8];
            acc[j] = __builtin_amdgcn_mfma_f32_16x16x32_bf16(af, bfr, acc[j], 0, 0, 0);
        }
    }
    #pragma unroll
    for (int j = 0; j < 4; j++) {
        int gn = n0 + j * 16 + mr;
        #pragma unroll
        for (int r = 0; r < 4; r++) {
            int gm = m0 + wave * 16 + q * 4 + r;
            float v = acc[j][r];
            if (rowbias) v += rowbias[(long)bz * M + gm];
            v *= scale;
            long cidx = (long)bz * sC + (long)gm * N + gn;
            if (flags & 1) ((unsigned short*)Cout)[cidx] = f2bf(v);
            else           ((float*)Cout)[cidx] = v;
        }
    }
}

// ---------------- fused fwx GEMM (bt): C1=A1@Bt^T, C2=A2@Bt^T, shared B ----------------
// 512 threads: two 4-wave groups each cover half of K (=L); f32 LDS reduction at end.
// Rationale: M=64 forces 64x64 tiles -> 256 blocks = 1 block/CU; at 256 threads that is
// 1 wave/SIMD (no latency hiding). K-split doubles waves/CU and halves loop depth.
__launch_bounds__(512)
__global__ void k_gemm_fw2(const unsigned short* __restrict__ A1,   // a_fw [B,64,L]
                           const unsigned short* __restrict__ A2,   // b_fw
                           const unsigned short* __restrict__ Bt,   // x_bfT [B,D,L]
                           unsigned short* __restrict__ C1,         // fwx_a [B,64,D]
                           unsigned short* __restrict__ C2)
{
    __shared__ __align__(16) unsigned short As1[2][64 * 32];
    __shared__ __align__(16) unsigned short As2[2][64 * 32];
    __shared__ __align__(16) unsigned short Bs[2][64 * 32];
    __shared__ float Red[2][64][65];            // +1 pad: conflict-free f32 reduce
    const int bz = blockIdx.z;
    const int n0 = blockIdx.x * 64;
    const int tid = threadIdx.x;
    const int grp = tid >> 8;                   // K-half group
    const int gtid = tid & 255;
    const int wave = gtid >> 6, lane = tid & 63;
    const int lrow = gtid >> 2, lk = (gtid & 3) * 8;
    const int q = lane >> 4, mr = lane & 15;
    const int kb = grp * (L_SZ / 2);

    const unsigned short* a1p = A1 + ((long)bz * NUM_EXP + lrow) * L_SZ + kb + lk;
    const unsigned short* a2p = A2 + ((long)bz * NUM_EXP + lrow) * L_SZ + kb + lk;
    const unsigned short* bp  = Bt + ((long)bz * D_MODEL + n0 + lrow) * L_SZ + kb + lk;

    floatx4 acc1[4], acc2[4];
    floatx4 z4 = {0.f, 0.f, 0.f, 0.f};
    #pragma unroll
    for (int j = 0; j < 4; j++) { acc1[j] = z4; acc2[j] = z4; }

    for (int k0 = 0; k0 < L_SZ / 2; k0 += 32) {
        __syncthreads();
        *(ushort8*)&As1[grp][lrow * 32 + lk] = *(const ushort8*)(a1p + k0);
        *(ushort8*)&As2[grp][lrow * 32 + lk] = *(const ushort8*)(a2p + k0);
        *(ushort8*)&Bs[grp][lrow * 32 + lk]  = *(const ushort8*)(bp + k0);
        __syncthreads();
        bf16x8 f1 = *(const bf16x8*)&As1[grp][(wave * 16 + mr) * 32 + q * 8];
        bf16x8 f2 = *(const bf16x8*)&As2[grp][(wave * 16 + mr) * 32 + q * 8];
        #pragma unroll
        for (int j = 0; j < 4; j++) {
            bf16x8 bb = *(const bf16x8*)&Bs[grp][(j * 16 + mr) * 32 + q * 8];
            acc1[j] = __builtin_amdgcn_mfma_f32_16x16x32_bf16(f1, bb, acc1[j], 0, 0, 0);
            acc2[j] = __builtin_amdgcn_mfma_f32_16x16x32_bf16(f2, bb, acc2[j], 0, 0, 0);
        }
    }
    __syncthreads();
    if (grp == 1) {
        #pragma unroll
        for (int j = 0; j < 4; j++)
            #pragma unroll
            for (int r = 0; r < 4; r++) {
                int gm = wave * 16 + q * 4 + r;
                Red[0][gm][j * 16 + mr] = acc1[j][r];
                Red[1][gm][j * 16 + mr] = acc2[j][r];
            }
    }
    __syncthreads();
    if (grp == 0) {
        #pragma unroll
        for (int j = 0; j < 4; j++) {
            int gn = n0 + j * 16 + mr;
            #pragma unroll
            for (int r = 0; r < 4; r++) {
                int gm = wave * 16 + q * 4 + r;
                long cidx = ((long)bz * NUM_EXP + gm) * D_MODEL + gn;
                C1[cidx] = f2bf(acc1[j][r] + Red[0][gm][j * 16 + mr]);
                C2[cidx] = f2bf(acc2[j][r] + Red[1][gm][j * 16 + mr]);
            }
        }
    }
}

// ---------------- fused cls GEMM (bt): side = blockIdx.z>>4 ----------------
// cls[e,d] = fwx[e,:]·W[d,:] + wsum[e]*bias[d] + biasE[e,d]; split hi/lo, transposed [d,e]
__launch_bounds__(256)
__global__ void k_gemm_cls(const unsigned short* __restrict__ fwxA, const unsigned short* __restrict__ fwxB,
                           const unsigned short* __restrict__ Wa_, const unsigned short* __restrict__ Wb_,
                           const float* __restrict__ ba_, const float* __restrict__ bb_,
                           const float* __restrict__ wsA, const float* __restrict__ wsB,
                           const float* __restrict__ biasE,
                           unsigned short* __restrict__ aHi, unsigned short* __restrict__ aLo,
                           unsigned short* __restrict__ bHi, unsigned short* __restrict__ bLo)
{
    __shared__ __align__(16) unsigned short As[64 * 32];
    __shared__ __align__(16) unsigned short Bs[64 * 32];
    const int zz = blockIdx.z;
    const int side = zz >> 4, bz = zz & 15;
    const unsigned short* Ab = (side ? fwxB : fwxA) + (long)bz * NUM_EXP * D_MODEL;
    const unsigned short* Bb = side ? Wb_ : Wa_;
    const float* cb = side ? bb_ : ba_;
    const float* rw = (side ? wsB : wsA) + bz * NUM_EXP;
    const float* bE = biasE + (long)bz * NUM_EXP * D_MODEL;
    unsigned short* oHi = (side ? bHi : aHi) + (long)bz * NUM_EXP * D_MODEL;
    unsigned short* oLo = (side ? bLo : aLo) + (long)bz * NUM_EXP * D_MODEL;

    const int tid = threadIdx.x;
    const int wave = tid >> 6, lane = tid & 63;
    const int n0 = blockIdx.x * 64;
    const int lrow = tid >> 2, lk = (tid & 3) * 8;
    const int q = lane >> 4, mr = lane & 15;

    floatx4 acc[4];
    floatx4 z4 = {0.f, 0.f, 0.f, 0.f};
    #pragma unroll
    for (int j = 0; j < 4; j++) acc[j] = z4;

    const unsigned short* Aptr = Ab + (long)lrow * D_MODEL + lk;
    const unsigned short* Bptr = Bb + (long)(n0 + lrow) * D_MODEL + lk;

    for (int k0 = 0; k0 < D_MODEL; k0 += 32) {
        __syncthreads();
        *(ushort8*)&As[lrow * 32 + lk] = *(const ushort8*)(Aptr + k0);
        *(ushort8*)&Bs[lrow * 32 + lk] = *(const ushort8*)(Bptr + k0);
        __syncthreads();
        bf16x8 af = *(const bf16x8*)&As[(wave * 16 + mr) * 32 + q * 8];
        #pragma unroll
        for (int j = 0; j < 4; j++) {
            bf16x8 bfr = *(const bf16x8*)&Bs[(j * 16 + mr) * 32 + q * 8];
            acc[j] = __builtin_amdgcn_mfma_f32_16x16x32_bf16(af, bfr, acc[j], 0, 0, 0);
        }
    }
    #pragma unroll
    for (int j = 0; j < 4; j++) {
        int gn = n0 + j * 16 + mr;          // d
        float cbv = cb[gn];
        #pragma unroll
        for (int r = 0; r < 4; r++) {
            int gm = wave * 16 + q * 4 + r; // e
            float v = acc[j][r] + rw[gm] * cbv + bE[(long)gm * D_MODEL + gn];
            unsigned short hi = f2bf(v);
            long tix = (long)gn * NUM_EXP + gm;
            oHi[tix] = hi;
            oLo[tix] = f2bf(v - bf2f(hi));
        }
    }
}

// ---------------- selector GEMM: 256x256 tile, 8-wave, 2-barrier/K-tile pipelined ----------------
// Minimal-barrier schedule. Per K-tile (BK=64, two K-halves kh0/kh1):
//   issue all kh0+b1 ds_reads, stage t+1 kh1 -> opposite buffer;
//   counted lgkmcnt so sub-cluster 2's reads finish under sub-cluster 1's MFMAs;
//   B1 after lgkmcnt(0): all waves done READING kh0 -> safe to stage t+2 kh0 over it;
//   counted vmcnt(4) (never 0) proves tile t+1 landed; B2 broadcasts it.
// Tail stages clamp to tile 15: same-address same-data rewrites (benign).
// Frag live-set <= 16 b128 (64 VGPR) keeps total regs ~248 -> 2 waves/SIMD.
__launch_bounds__(512, 2)
__global__ void k_gemm_sel(const unsigned short* __restrict__ A,
                           const unsigned short* __restrict__ Bm,
                           const float* __restrict__ bias,
                           unsigned short* __restrict__ C)
{
    // [buf][khalf][256 rows][4 groups x 8 shorts], groups XOR-permuted per row-pair
    __shared__ __align__(16) unsigned short As[2][2][8192];
    __shared__ __align__(16) unsigned short Bs[2][2][8192];

    const int tid = threadIdx.x;
    const int wid = tid >> 6, lane = tid & 63;
    const int q = lane >> 4, mr = lane & 15;
    const int wm = wid >> 2, wn = wid & 3;           // 2x4 wave grid, 128x64 per wave
    const int kread = (q ^ ((mr >> 1) & 3)) * 8;

    // XCD-aware bijective swizzle: 512 blocks = 8 XCDs x 64; each XCD owns 16 m-panels
    const int bid = blockIdx.x;
    const int wg = (bid & 7) * 64 + (bid >> 3);
    const int m0 = (wg >> 2) * 256;
    const int n0 = (wg & 3) * 256;

    const unsigned short* Ag = A + (long)m0 * 1024;
    const unsigned short* Bg = Bm + (long)n0 * 1024;

    // staging: slot s = j*512+tid -> row s>>2, phys group s&3 (j=1: row += 128, same key)
    const int srow = tid >> 2;
    const int sgrp = (tid & 3) ^ ((srow >> 1) & 3);
    const long soff = (long)srow * 1024 + sgrp * 8;
    const int ldst = wid * 64 * 8;                   // wave base (shorts) within region

    auto STAGE_H = [&](int tile, int kh, int isB) {
        if (tile > 15) tile = 15;                    // tail: redundant same-data re-stage
        const unsigned short* src = (isB ? Bg : Ag) + (long)tile * 64 + kh * 32 + soff;
        unsigned short* dst = (isB ? &Bs[0][0][0] : &As[0][0][0])
                              + ((tile & 1) * 2 + kh) * 8192 + ldst;
        GLD16(src, dst);
        GLD16(src + 128 * 1024, dst + 4096);
    };

    floatx4 acc[8][4];
    floatx4 z4 = {0.f, 0.f, 0.f, 0.f};
    #pragma unroll
    for (int i = 0; i < 8; i++)
        #pragma unroll
        for (int j = 0; j < 4; j++) acc[i][j] = z4;

    // prologue: tile0 (kh0+kh1) + tile1 kh0  = 12 GLD/thread in flight
    STAGE_H(0, 0, 0); STAGE_H(0, 0, 1);
    STAGE_H(0, 1, 0); STAGE_H(0, 1, 1);
    STAGE_H(1, 0, 0); STAGE_H(1, 0, 1);
    asm volatile("s_waitcnt vmcnt(4)" ::: "memory");   // tile0 landed; tile1 kh0 in flight
    __builtin_amdgcn_s_barrier();

    for (int t = 0; t < 16; t++) {
        const unsigned short* Ab_ = &As[t & 1][0][0];
        const unsigned short* Bb_ = &Bs[t & 1][0][0];
        bf16x8 b0[4], b1[4], a0[4], a1[4];
        #pragma unroll
        for (int j = 0; j < 4; j++)
            b0[j] = *(const bf16x8*)&Bb_[(wn * 64 + j * 16 + mr) * 32 + kread];
        #pragma unroll
        for (int i = 0; i < 4; i++)
            a0[i] = *(const bf16x8*)&Ab_[(wm * 128 + i * 16 + mr) * 32 + kread];
        STAGE_H(t + 1, 1, 0); STAGE_H(t + 1, 1, 1);        // -> opposite buffer
        #pragma unroll
        for (int j = 0; j < 4; j++)
            b1[j] = *(const bf16x8*)&Bb_[8192 + (wn * 64 + j * 16 + mr) * 32 + kread];
        asm volatile("s_waitcnt lgkmcnt(4)" ::: "memory"); // b0,a0 ready (b1 may fly)
        __builtin_amdgcn_sched_barrier(0);
        __builtin_amdgcn_s_setprio(1);
        #pragma unroll
        for (int i = 0; i < 4; i++)
            #pragma unroll
            for (int j = 0; j < 4; j++)
                acc[i][j] = __builtin_amdgcn_mfma_f32_16x16x32_bf16(a0[i], b0[j], acc[i][j], 0, 0, 0);
        __builtin_amdgcn_s_setprio(0);
        #pragma unroll
        for (int i = 0; i < 4; i++)
            a1[i] = *(const bf16x8*)&Ab_[(wm * 128 + 64 + i * 16 + mr) * 32 + kread];
        asm volatile("s_waitcnt lgkmcnt(0)" ::: "memory");
        __builtin_amdgcn_sched_barrier(0);
        __builtin_amdgcn_s_setprio(1);
        #pragma unroll
        for (int i = 0; i < 4; i++)
            #pragma unroll
            for (int j = 0; j < 4; j++)
                acc[4 + i][j] = __builtin_amdgcn_mfma_f32_16x16x32_bf16(a1[i], b0[j], acc[4 + i][j], 0, 0, 0);
        __builtin_amdgcn_s_setprio(0);
        __builtin_amdgcn_s_barrier();                      // B1: all waves done reading kh0
        STAGE_H(t + 2, 0, 0); STAGE_H(t + 2, 0, 1);        // overwrite this buffer's kh0
        #pragma unroll
        for (int i = 0; i < 4; i++)
            a0[i] = *(const bf16x8*)&Ab_[8192 + (wm * 128 + i * 16 + mr) * 32 + kread];
        #pragma unroll
        for (int i = 0; i < 4; i++)
            a1[i] = *(const bf16x8*)&Ab_[8192 + (wm * 128 + 64 + i * 16 + mr) * 32 + kread];
        asm volatile("s_waitcnt vmcnt(4)" ::: "memory");   // tile t+1 fully landed
        asm volatile("s_waitcnt lgkmcnt(4)" ::: "memory"); // kh1 a0 ready
        __builtin_amdgcn_sched_barrier(0);
        __builtin_amdgcn_s_setprio(1);
        #pragma unroll
        for (int i = 0; i < 4; i++)
            #pragma unroll
            for (int j = 0; j < 4; j++)
                acc[i][j] = __builtin_amdgcn_mfma_f32_16x16x32_bf16(a0[i], b1[j], acc[i][j], 0, 0, 0);
        __builtin_amdgcn_s_setprio(0);
        asm volatile("s_waitcnt lgkmcnt(0)" ::: "memory");
        __builtin_amdgcn_sched_barrier(0);
        __builtin_amdgcn_s_setprio(1);
        #pragma unroll
        for (int i = 0; i < 4; i++)
            #pragma unroll
            for (int j = 0; j < 4; j++)
                acc[4 + i][j] = __builtin_amdgcn_mfma_f32_16x16x32_bf16(a1[i], b1[j], acc[4 + i][j], 0, 0, 0);
        __builtin_amdgcn_s_setprio(0);
        __builtin_amdgcn_s_barrier();                      // B2: vmcnt(4) passed by all
    }
    asm volatile("s_waitcnt vmcnt(0)" ::: "memory");   // drain tail DMA before exit

    #pragma unroll
    for (int i = 0; i < 8; i++) {
        #pragma unroll
        for (int j = 0; j < 4; j++) {
            const int gn = n0 + wn * 64 + j * 16 + mr;
            const float cbv = bias[gn];
            #pragma unroll
            for (int r = 0; r < 4; r++) {
                const int gm = m0 + wm * 128 + i * 16 + q * 4 + r;
                C[(long)gm * 1024 + gn] = f2bf(acc[i][j][r] + cbv);
            }
        }
    }
}

// ---------------- forward norm over L (masked); wsum = S/(S+eps) ----------------
__global__ void k_fwnorm(const float* __restrict__ z, const int* __restrict__ mask,
                         unsigned short* __restrict__ a_fw, unsigned short* __restrict__ b_fw,
                         float* __restrict__ wsum_a, float* __restrict__ wsum_b)
{
    int be = blockIdx.x;
    int b = be >> 6;
    const float* zr = z + (long)be * L_SZ;
    const int* mr = mask + (long)b * L_SZ;
    int tid = threadIdx.x;
    float sa = 0.f, sb = 0.f;
    for (int l = tid; l < L_SZ; l += 256) {
        float v = zr[l];
        if (mr[l] != 0) { sa += fmaxf(v, 0.f); sb += fmaxf(-v, 0.f); }
    }
    #pragma unroll
    for (int o = 32; o > 0; o >>= 1) { sa += __shfl_down(sa, o); sb += __shfl_down(sb, o); }
    __shared__ float red[8];
    int wave = tid >> 6, lane = tid & 63;
    if (lane == 0) { red[wave] = sa; red[4 + wave] = sb; }
    __syncthreads();
    float ta = red[0] + red[1] + red[2] + red[3];
    float tb = red[4] + red[5] + red[6] + red[7];
    float ia = 1.f / (ta + 1e-9f), ib = 1.f / (tb + 1e-9f);
    if (tid == 0) { wsum_a[be] = ta * ia; wsum_b[be] = tb * ib; }
    for (int l = tid; l < L_SZ; l += 256) {
        float v = zr[l];
        float m = (mr[l] != 0) ? 1.f : 0.f;
        a_fw[(long)be * L_SZ + l] = f2bf(fmaxf(v, 0.f) * m * ia);
        b_fw[(long)be * L_SZ + l] = f2bf(fmaxf(-v, 0.f) * m * ib);
    }
}

// ---------------- backward norm over E (unmasked), bf16 out ----------------
__global__ void k_bwnorm(const float* __restrict__ z, unsigned short* __restrict__ a_bw,
                         unsigned short* __restrict__ b_bw)
{
    int r = blockIdx.x * 256 + threadIdx.x;
    int b = r >> 11, l = r & 2047;
    const float* zb = z + (long)b * NUM_EXP * L_SZ + l;
    float sa = 0.f, sb = 0.f;
    float va[NUM_EXP];
    #pragma unroll 8
    for (int e = 0; e < NUM_EXP; e++) {
        float v = zb[(long)e * L_SZ];
        va[e] = v;
        sa += fmaxf(v, 0.f); sb += fmaxf(-v, 0.f);
    }
    float ia = 1.f / (sa + 1e-9f), ib = 1.f / (sb + 1e-9f);
    unsigned short* ar = a_bw + (long)r * NUM_EXP;
    unsigned short* br = b_bw + (long)r * NUM_EXP;
    #pragma unroll 8
    for (int e = 0; e < NUM_EXP; e++) {
        float v = va[e];
        ar[e] = f2bf(fmaxf(v, 0.f) * ia);
        br[e] = f2bf(fmaxf(-v, 0.f) * ib);
    }
}

// ---------------- final: out = sig(sel)*(aw@clsA) + (1-sig)*(bw@clsB) via MFMA ----------------
__launch_bounds__(256)
__global__ void k_final_mfma(const unsigned short* __restrict__ aw,
                             const unsigned short* __restrict__ bw,
                             const unsigned short* __restrict__ caHi,
                             const unsigned short* __restrict__ caLo,
                             const unsigned short* __restrict__ cbHi,
                             const unsigned short* __restrict__ cbLo,
                             const unsigned short* __restrict__ selbf,   // bf16 logits
                             float* __restrict__ out)
{
    __shared__ __align__(16) unsigned short Aa[64 * 72];
    __shared__ __align__(16) unsigned short Ab[64 * 72];
    __shared__ __align__(16) unsigned short BaH[64 * 72];
    __shared__ __align__(16) unsigned short BaL[64 * 72];
    __shared__ __align__(16) unsigned short BbH[64 * 72];
    __shared__ __align__(16) unsigned short BbL[64 * 72];
    const int bz = blockIdx.z;
    const int l0 = blockIdx.y * 64, d0 = blockIdx.x * 64;
    const int tid = threadIdx.x;
    const int wave = tid >> 6, lane = tid & 63;
    const int q = lane >> 4, mr = lane & 15;

    const unsigned short* awb = aw + ((long)bz * L_SZ + l0) * NUM_EXP;
    const unsigned short* bwb = bw + ((long)bz * L_SZ + l0) * NUM_EXP;
    const long cbase = ((long)bz * D_MODEL + d0) * NUM_EXP;

    #pragma unroll
    for (int c = 0; c < 2; c++) {
        int idx = c * 256 + tid;
        int row = idx >> 3, kc = (idx & 7) * 8;
        int lw = row * 72 + kc;
        long ga = (long)row * NUM_EXP + kc;
        *(ushort8*)&Aa[lw]  = *(const ushort8*)(awb + ga);
        *(ushort8*)&Ab[lw]  = *(const ushort8*)(bwb + ga);
        *(ushort8*)&BaH[lw] = *(const ushort8*)(caHi + cbase + ga);
        *(ushort8*)&BaL[lw] = *(const ushort8*)(caLo + cbase + ga);
        *(ushort8*)&BbH[lw] = *(const ushort8*)(cbHi + cbase + ga);
        *(ushort8*)&BbL[lw] = *(const ushort8*)(cbLo + cbase + ga);
    }
    __syncthreads();

    floatx4 accA[4], accB[4];
    floatx4 z4 = {0.f, 0.f, 0.f, 0.f};
    #pragma unroll
    for (int j = 0; j < 4; j++) { accA[j] = z4; accB[j] = z4; }

    #pragma unroll
    for (int ks = 0; ks < 2; ks++) {
        int ko = ks * 32 + q * 8;
        bf16x8 fa = *(const bf16x8*)&Aa[(wave * 16 + mr) * 72 + ko];
        bf16x8 fb = *(const bf16x8*)&Ab[(wave * 16 + mr) * 72 + ko];
        #pragma unroll
        for (int j = 0; j < 4; j++) {
            int bo = (j * 16 + mr) * 72 + ko;
            accA[j] = __builtin_amdgcn_mfma_f32_16x16x32_bf16(fa, *(const bf16x8*)&BaH[bo], accA[j], 0, 0, 0);
            accA[j] = __builtin_amdgcn_mfma_f32_16x16x32_bf16(fa, *(const bf16x8*)&BaL[bo], accA[j], 0, 0, 0);
            accB[j] = __builtin_amdgcn_mfma_f32_16x16x32_bf16(fb, *(const bf16x8*)&BbH[bo], accB[j], 0, 0, 0);
            accB[j] = __builtin_amdgcn_mfma_f32_16x16x32_bf16(fb, *(const bf16x8*)&BbL[bo], accB[j], 0, 0, 0);
        }
    }

    #pragma unroll
    for (int j = 0; j < 4; j++) {
        #pragma unroll
        for (int r = 0; r < 4; r++) {
            int gl = l0 + wave * 16 + q * 4 + r;
            int gd = d0 + j * 16 + mr;
            long o = ((long)bz * L_SZ + gl) * D_MODEL + gd;
            float s = 1.f / (1.f + __expf(-bf2f(selbf[o])));
            out[o] = s * accA[j][r] + (1.f - s) * accB[j][r];
        }
    }
}

extern "C" void kernel_launch(void* const* d_in, const int* in_sizes, int n_in,
                              void* d_out, int out_size, void* d_ws, size_t ws_size,
                              hipStream_t stream)
{
    const float* x     = (const float*)d_in[0];
    const int*   nidx  = (const int*)d_in[1];
    const int*   mask  = (const int*)d_in[2];
    const float* q_emb = (const float*)d_in[3];
    const float* b_emb = (const float*)d_in[4];
    const float* Wk    = (const float*)d_in[5];
    const float* bk    = (const float*)d_in[6];
    const float* Wa    = (const float*)d_in[7];
    const float* ba    = (const float*)d_in[8];
    const float* Wb    = (const float*)d_in[9];
    const float* bb    = (const float*)d_in[10];
    const float* Ws    = (const float*)d_in[11];
    const float* bs    = (const float*)d_in[12];
    float* out = (float*)d_out;

    constexpr long BLD = (long)B_SZ * L_SZ * D_MODEL;
    constexpr long BEL = (long)B_SZ * NUM_EXP * L_SZ;
    constexpr long BED = (long)B_SZ * NUM_EXP * D_MODEL;
    constexpr long DD  = (long)D_MODEL * D_MODEL;

    char* w = (char*)d_ws;
    size_t off = 0;
    auto carve = [&](size_t bytes) { char* p = w + off; off += (bytes + 255) & ~(size_t)255; return p; };
    unsigned short* x_bf   = (unsigned short*)carve(BLD * 2);
    unsigned short* x_bfT  = (unsigned short*)carve(BLD * 2);  // later reused as sel logits
    unsigned short* wkT_bf = (unsigned short*)carve(DD * 2);
    unsigned short* wa_bf  = (unsigned short*)carve(DD * 2);
    unsigned short* wb_bf  = (unsigned short*)carve(DD * 2);
    unsigned short* ws_bf  = (unsigned short*)carve(DD * 2);
    unsigned short* qexp   = (unsigned short*)carve(BED * 2);
    float*          bias_e = (float*)carve(BED * 4);
    float*          qbk    = (float*)carve(B_SZ * NUM_EXP * 4);
    unsigned short* qk     = (unsigned short*)carve(BED * 2);
    float*          z      = (float*)carve(BEL * 4);
    unsigned short* a_fw   = (unsigned short*)carve(BEL * 2);
    unsigned short* b_fw   = (unsigned short*)carve(BEL * 2);
    float*          wsum_a = (float*)carve(B_SZ * NUM_EXP * 4);
    float*          wsum_b = (float*)carve(B_SZ * NUM_EXP * 4);
    unsigned short* a_bw   = (unsigned short*)carve(BEL * 2);
    unsigned short* b_bw   = (unsigned short*)carve(BEL * 2);
    unsigned short* fwx_a  = (unsigned short*)carve(BED * 2);
    unsigned short* fwx_b  = (unsigned short*)carve(BED * 2);
    unsigned short* caHi   = (unsigned short*)carve(BED * 2);
    unsigned short* caLo   = (unsigned short*)carve(BED * 2);
    unsigned short* cbHi   = (unsigned short*)carve(BED * 2);
    unsigned short* cbLo   = (unsigned short*)carve(BED * 2);
    if (ws_size < off) return;
    unsigned short* selbf = x_bfT;  // x_bfT dead after fw2 GEMM; sel GEMM runs after it

    // 1. conversions / transposes
    k_convx<<<dim3(16, 32, B_SZ), 256, 0, stream>>>(x, x_bf, x_bfT);
    k_transw<<<dim3(16, 16), 256, 0, stream>>>(Wk, wkT_bf);
    k_convert3<<<(3 * DD) / 2048, 256, 0, stream>>>(Wa, Wb, Ws, wa_bf, wb_bf, ws_bf);
    k_gather<<<B_SZ * NUM_EXP, 256, 0, stream>>>(nidx, q_emb, b_emb, bk, qexp, bias_e, qbk);

    // 2. qk[e,n] = sum_d qexp[e,d] * WkT[n,d]   (bf16 out)
    k_gemm_bt<<<dim3(16, 1, B_SZ), 256, 0, stream>>>(qexp, wkT_bf, nullptr, qk,
        NUM_EXP, D_MODEL, D_MODEL, 1.f, 1, (long)NUM_EXP * D_MODEL, 0, (long)NUM_EXP * D_MODEL);

    // 3. z[e,l] = (qk[e,:]·x[l,:] + qbk[e]) / 32  (f32)
    k_gemm_bt<<<dim3(32, 1, B_SZ), 256, 0, stream>>>(qk, x_bf, qbk, z,
        NUM_EXP, L_SZ, D_MODEL, 1.f / 32.f, 0,
        (long)NUM_EXP * D_MODEL, (long)L_SZ * D_MODEL, (long)NUM_EXP * L_SZ);

    // 4. normalizations
    k_fwnorm<<<B_SZ * NUM_EXP, 256, 0, stream>>>(z, mask, a_fw, b_fw, wsum_a, wsum_b);
    k_bwnorm<<<(B_SZ * L_SZ) / 256, 256, 0, stream>>>(z, a_bw, b_bw);

    // 5. fwx_{a,b}[e,c] = sum_l fw[e,l]·xT[c,l]  (fused, shared B; 512 thr, K-split x2)
    k_gemm_fw2<<<dim3(16, 1, B_SZ), 512, 0, stream>>>(a_fw, b_fw, x_bfT, fwx_a, fwx_b);

    // 6. sel logits -> selbf (aliases x_bfT; runs AFTER fw2). 512 blocks = 128m x 4n.
    k_gemm_sel<<<512, 512, 0, stream>>>(x_bf, ws_bf, bs, selbf);

    // 7. cls (both sides fused), transposed split store
    k_gemm_cls<<<dim3(16, 1, 32), 256, 0, stream>>>(fwx_a, fwx_b, wa_bf, wb_bf, ba, bb,
        wsum_a, wsum_b, bias_e, caHi, caLo, cbHi, cbLo);

    // 8. final blend
    k_final_mfma<<<dim3(16, 32, B_SZ), 256, 0, stream>>>(a_bw, b_bw, caHi, caLo, cbHi, cbLo, selbf, out);
}

// Round 3
// 523.647 us; speedup vs baseline: 1.0473x; 1.0431x over previous
//
#include <hip/hip_runtime.h>
#include <math.h>

#define D_MODEL 1024
#define NUM_EXP 64
#define B_SZ 16
#define L_SZ 2048

using bf16x8  = __attribute__((ext_vector_type(8))) __bf16;
using floatx4 = __attribute__((ext_vector_type(4))) float;
using ushort8 = __attribute__((ext_vector_type(8))) unsigned short;
using ushort4v = __attribute__((ext_vector_type(4))) unsigned short;

__device__ __forceinline__ unsigned short f2bf(float f) {
    union { float f; unsigned u; } x; x.f = f;
    unsigned r = (x.u + 0x7fffu + ((x.u >> 16) & 1u)) >> 16;
    return (unsigned short)r;
}
__device__ __forceinline__ float bf2f(unsigned short h) {
    union { unsigned u; float f; } x; x.u = ((unsigned)h) << 16;
    return x.f;
}

// async 16B global->LDS (lds base wave-uniform; lane i lands at base+16*i)
#define GLD16(gp, lp) __builtin_amdgcn_global_load_lds( \
    (const __attribute__((address_space(1))) unsigned int*)(gp), \
    (__attribute__((address_space(3))) unsigned int*)(lp), 16, 0, 0)

// ---------------- x: f32 -> bf16, both [B,L,D] and transposed [B,D,L] ----------------
__global__ void k_convx(const float* __restrict__ in, unsigned short* __restrict__ outN,
                        unsigned short* __restrict__ outT)
{
    __shared__ unsigned short T[64][65];
    const int b = blockIdx.z;
    const int l0 = blockIdx.y * 64, c0 = blockIdx.x * 64;
    const int t = threadIdx.x;
    const int tr = t >> 4, tc = (t & 15) * 4;
    const float* src = in + ((long)b * L_SZ + l0) * D_MODEL + c0;
    unsigned short* dN = outN + ((long)b * L_SZ + l0) * D_MODEL + c0;
    #pragma unroll
    for (int i = 0; i < 4; i++) {
        int r = tr + i * 16;
        float4 v = *(const float4*)(src + (long)r * D_MODEL + tc);
        ushort4v u; u[0]=f2bf(v.x); u[1]=f2bf(v.y); u[2]=f2bf(v.z); u[3]=f2bf(v.w);
        *(ushort4v*)(dN + (long)r * D_MODEL + tc) = u;
        T[r][tc+0]=u[0]; T[r][tc+1]=u[1]; T[r][tc+2]=u[2]; T[r][tc+3]=u[3];
    }
    __syncthreads();
    unsigned short* dT = outT + ((long)b * D_MODEL + c0) * L_SZ + l0;
    #pragma unroll
    for (int i = 0; i < 4; i++) {
        int c = tr + i * 16;
        ushort4v u;
        u[0]=T[tc+0][c]; u[1]=T[tc+1][c]; u[2]=T[tc+2][c]; u[3]=T[tc+3][c];
        *(ushort4v*)(dT + (long)c * L_SZ + tc) = u;
    }
}

// ---------------- fused prep: [0,256) Wk transpose | [256,1792) Wa/Wb/Ws conv | [1792,2816) gather ----------------
__global__ void k_prep(const float* __restrict__ Wk,
                       const float* __restrict__ Wa, const float* __restrict__ Wb,
                       const float* __restrict__ Ws,
                       const int* __restrict__ idx, const float* __restrict__ q_emb,
                       const float* __restrict__ b_emb, const float* __restrict__ bk,
                       unsigned short* __restrict__ wkT,
                       unsigned short* __restrict__ oa, unsigned short* __restrict__ ob,
                       unsigned short* __restrict__ oc,
                       unsigned short* __restrict__ qexp, float* __restrict__ bias_exp,
                       float* __restrict__ qbk)
{
    __shared__ unsigned short T[64][65];
    __shared__ float red[4];
    const int blk = blockIdx.x;
    const int t = threadIdx.x;
    if (blk < 256) {
        // Wk: f32 [K,N] -> bf16 transposed [N,K]
        const int r0 = (blk >> 4) * 64, c0 = (blk & 15) * 64;
        const int tr = t >> 4, tc = (t & 15) * 4;
        const float* src = Wk + (long)r0 * D_MODEL + c0;
        #pragma unroll
        for (int i = 0; i < 4; i++) {
            int r = tr + i * 16;
            float4 v = *(const float4*)(src + (long)r * D_MODEL + tc);
            T[r][tc+0]=f2bf(v.x); T[r][tc+1]=f2bf(v.y); T[r][tc+2]=f2bf(v.z); T[r][tc+3]=f2bf(v.w);
        }
        __syncthreads();
        unsigned short* dT = wkT + ((long)c0) * D_MODEL + r0;
        #pragma unroll
        for (int i = 0; i < 4; i++) {
            int c = tr + i * 16;
            ushort4v u;
            u[0]=T[tc+0][c]; u[1]=T[tc+1][c]; u[2]=T[tc+2][c]; u[3]=T[tc+3][c];
            *(ushort4v*)(dT + (long)c * D_MODEL + tc) = u;
        }
    } else if (blk < 256 + 1536) {
        long i = ((long)(blk - 256) * 256 + t) * 8;
        int which = (int)(i >> 20);
        long off = i & ((1L << 20) - 1);
        const float* src = which == 0 ? Wa : which == 1 ? Wb : Ws;
        unsigned short* dst = which == 0 ? oa : which == 1 ? ob : oc;
        float4 v0 = *(const float4*)(src + off);
        float4 v1 = *(const float4*)(src + off + 4);
        ushort8 r;
        r[0]=f2bf(v0.x); r[1]=f2bf(v0.y); r[2]=f2bf(v0.z); r[3]=f2bf(v0.w);
        r[4]=f2bf(v1.x); r[5]=f2bf(v1.y); r[6]=f2bf(v1.z); r[7]=f2bf(v1.w);
        *(ushort8*)(dst + off) = r;
    } else {
        const int be = blk - 1792;
        const int row = idx[be];
        const float* qs = q_emb + (long)row * D_MODEL;
        const float* bsrc = b_emb + (long)row * D_MODEL;
        float4 q4 = *(const float4*)(qs + t * 4);
        float4 k4 = *(const float4*)(bk + t * 4);
        float4 b4 = *(const float4*)(bsrc + t * 4);
        ushort4v r; r[0]=f2bf(q4.x); r[1]=f2bf(q4.y); r[2]=f2bf(q4.z); r[3]=f2bf(q4.w);
        *(ushort4v*)(qexp + (long)be * D_MODEL + t * 4) = r;
        *(float4*)(bias_exp + (long)be * D_MODEL + t * 4) = b4;
        float p = q4.x*k4.x + q4.y*k4.y + q4.z*k4.z + q4.w*k4.w;
        #pragma unroll
        for (int o = 32; o > 0; o >>= 1) p += __shfl_down(p, o);
        if ((t & 63) == 0) red[t >> 6] = p;
        __syncthreads();
        if (t == 0) qbk[be] = red[0] + red[1] + red[2] + red[3];
    }
}

// ---------------- generic bt GEMM: C = epi(A[M,K] @ B[N,K]^T) ----------------
// v = (acc + rowbias[gm]) * scale ; flags: bit0 = bf16 store (else f32)
__launch_bounds__(256)
__global__ void k_gemm_bt(const unsigned short* __restrict__ A,
                          const unsigned short* __restrict__ Bm,
                          const float* __restrict__ rowbias,
                          void* __restrict__ Cout,
                          int M, int N, int K, float scale, int flags,
                          long sA, long sB, long sC)
{
    __shared__ __align__(16) unsigned short As[64 * 32];
    __shared__ __align__(16) unsigned short Bs[64 * 32];
    const int bz = blockIdx.z;
    const unsigned short* Ab = A + (long)bz * sA;
    const unsigned short* Bb = Bm + (long)bz * sB;
    const int tid = threadIdx.x;
    const int wave = tid >> 6, lane = tid & 63;
    const int m0 = blockIdx.y * 64, n0 = blockIdx.x * 64;
    const int lrow = tid >> 2, lk = (tid & 3) * 8;
    const int q = lane >> 4, mr = lane & 15;

    floatx4 acc[4];
    floatx4 z4 = {0.f, 0.f, 0.f, 0.f};
    #pragma unroll
    for (int j = 0; j < 4; j++) acc[j] = z4;

    const unsigned short* Aptr = Ab + (long)(m0 + lrow) * K + lk;
    const unsigned short* Bptr = Bb + (long)(n0 + lrow) * K + lk;

    for (int k0 = 0; k0 < K; k0 += 32) {
        __syncthreads();
        *(ushort8*)&As[lrow * 32 + lk] = *(const ushort8*)(Aptr + k0);
        *(ushort8*)&Bs[lrow * 32 + lk] = *(const ushort8*)(Bptr + k0);
        __syncthreads();
        bf16x8 af = *(const bf16x8*)&As[(wave * 16 + mr) * 32 + q * 8];
        #pragma unroll
        for (int j = 0; j < 4; j++) {
            bf16x8 bfr = *(const bf16x8*)&Bs[(j * 16 + mr) * 32 + q * 8];
            acc[j] = __builtin_amdgcn_mfma_f32_16x16x32_bf16(af, bfr, acc[j], 0, 0, 0);
        }
    }
    #pragma unroll
    for (int j = 0; j < 4; j++) {
        int gn = n0 + j * 16 + mr;
        #pragma unroll
        for (int r = 0; r < 4; r++) {
            int gm = m0 + wave * 16 + q * 4 + r;
            float v = acc[j][r];
            if (rowbias) v += rowbias[(long)bz * M + gm];
            v *= scale;
            long cidx = (long)bz * sC + (long)gm * N + gn;
            if (flags & 1) ((unsigned short*)Cout)[cidx] = f2bf(v);
            else           ((float*)Cout)[cidx] = v;
        }
    }
}

// ---------------- fused fwx GEMM (bt): C1=A1@Bt^T, C2=A2@Bt^T, shared B ----------------
// 512 threads: two 4-wave groups each cover half of K (=L); f32 LDS reduction at end.
__launch_bounds__(512)
__global__ void k_gemm_fw2(const unsigned short* __restrict__ A1,   // a_fw [B,64,L]
                           const unsigned short* __restrict__ A2,   // b_fw
                           const unsigned short* __restrict__ Bt,   // x_bfT [B,D,L]
                           unsigned short* __restrict__ C1,         // fwx_a [B,64,D]
                           unsigned short* __restrict__ C2)
{
    __shared__ __align__(16) unsigned short As1[2][64 * 32];
    __shared__ __align__(16) unsigned short As2[2][64 * 32];
    __shared__ __align__(16) unsigned short Bs[2][64 * 32];
    __shared__ float Red[2][64][65];            // +1 pad: conflict-free f32 reduce
    const int bz = blockIdx.z;
    const int n0 = blockIdx.x * 64;
    const int tid = threadIdx.x;
    const int grp = tid >> 8;                   // K-half group
    const int gtid = tid & 255;
    const int wave = gtid >> 6, lane = tid & 63;
    const int lrow = gtid >> 2, lk = (gtid & 3) * 8;
    const int q = lane >> 4, mr = lane & 15;
    const int kb = grp * (L_SZ / 2);

    const unsigned short* a1p = A1 + ((long)bz * NUM_EXP + lrow) * L_SZ + kb + lk;
    const unsigned short* a2p = A2 + ((long)bz * NUM_EXP + lrow) * L_SZ + kb + lk;
    const unsigned short* bp  = Bt + ((long)bz * D_MODEL + n0 + lrow) * L_SZ + kb + lk;

    floatx4 acc1[4], acc2[4];
    floatx4 z4 = {0.f, 0.f, 0.f, 0.f};
    #pragma unroll
    for (int j = 0; j < 4; j++) { acc1[j] = z4; acc2[j] = z4; }

    for (int k0 = 0; k0 < L_SZ / 2; k0 += 32) {
        __syncthreads();
        *(ushort8*)&As1[grp][lrow * 32 + lk] = *(const ushort8*)(a1p + k0);
        *(ushort8*)&As2[grp][lrow * 32 + lk] = *(const ushort8*)(a2p + k0);
        *(ushort8*)&Bs[grp][lrow * 32 + lk]  = *(const ushort8*)(bp + k0);
        __syncthreads();
        bf16x8 f1 = *(const bf16x8*)&As1[grp][(wave * 16 + mr) * 32 + q * 8];
        bf16x8 f2 = *(const bf16x8*)&As2[grp][(wave * 16 + mr) * 32 + q * 8];
        #pragma unroll
        for (int j = 0; j < 4; j++) {
            bf16x8 bb = *(const bf16x8*)&Bs[grp][(j * 16 + mr) * 32 + q * 8];
            acc1[j] = __builtin_amdgcn_mfma_f32_16x16x32_bf16(f1, bb, acc1[j], 0, 0, 0);
            acc2[j] = __builtin_amdgcn_mfma_f32_16x16x32_bf16(f2, bb, acc2[j], 0, 0, 0);
        }
    }
    __syncthreads();
    if (grp == 1) {
        #pragma unroll
        for (int j = 0; j < 4; j++)
            #pragma unroll
            for (int r = 0; r < 4; r++) {
                int gm = wave * 16 + q * 4 + r;
                Red[0][gm][j * 16 + mr] = acc1[j][r];
                Red[1][gm][j * 16 + mr] = acc2[j][r];
            }
    }
    __syncthreads();
    if (grp == 0) {
        #pragma unroll
        for (int j = 0; j < 4; j++) {
            int gn = n0 + j * 16 + mr;
            #pragma unroll
            for (int r = 0; r < 4; r++) {
                int gm = wave * 16 + q * 4 + r;
                long cidx = ((long)bz * NUM_EXP + gm) * D_MODEL + gn;
                C1[cidx] = f2bf(acc1[j][r] + Red[0][gm][j * 16 + mr]);
                C2[cidx] = f2bf(acc2[j][r] + Red[1][gm][j * 16 + mr]);
            }
        }
    }
}

// ---------------- fused cls GEMM (bt): side = blockIdx.z>>4 ----------------
__launch_bounds__(256)
__global__ void k_gemm_cls(const unsigned short* __restrict__ fwxA, const unsigned short* __restrict__ fwxB,
                           const unsigned short* __restrict__ Wa_, const unsigned short* __restrict__ Wb_,
                           const float* __restrict__ ba_, const float* __restrict__ bb_,
                           const float* __restrict__ wsA, const float* __restrict__ wsB,
                           const float* __restrict__ biasE,
                           unsigned short* __restrict__ aHi, unsigned short* __restrict__ aLo,
                           unsigned short* __restrict__ bHi, unsigned short* __restrict__ bLo)
{
    __shared__ __align__(16) unsigned short As[64 * 32];
    __shared__ __align__(16) unsigned short Bs[64 * 32];
    const int zz = blockIdx.z;
    const int side = zz >> 4, bz = zz & 15;
    const unsigned short* Ab = (side ? fwxB : fwxA) + (long)bz * NUM_EXP * D_MODEL;
    const unsigned short* Bb = side ? Wb_ : Wa_;
    const float* cb = side ? bb_ : ba_;
    const float* rw = (side ? wsB : wsA) + bz * NUM_EXP;
    const float* bE = biasE + (long)bz * NUM_EXP * D_MODEL;
    unsigned short* oHi = (side ? bHi : aHi) + (long)bz * NUM_EXP * D_MODEL;
    unsigned short* oLo = (side ? bLo : aLo) + (long)bz * NUM_EXP * D_MODEL;

    const int tid = threadIdx.x;
    const int wave = tid >> 6, lane = tid & 63;
    const int n0 = blockIdx.x * 64;
    const int lrow = tid >> 2, lk = (tid & 3) * 8;
    const int q = lane >> 4, mr = lane & 15;

    floatx4 acc[4];
    floatx4 z4 = {0.f, 0.f, 0.f, 0.f};
    #pragma unroll
    for (int j = 0; j < 4; j++) acc[j] = z4;

    const unsigned short* Aptr = Ab + (long)lrow * D_MODEL + lk;
    const unsigned short* Bptr = Bb + (long)(n0 + lrow) * D_MODEL + lk;

    for (int k0 = 0; k0 < D_MODEL; k0 += 32) {
        __syncthreads();
        *(ushort8*)&As[lrow * 32 + lk] = *(const ushort8*)(Aptr + k0);
        *(ushort8*)&Bs[lrow * 32 + lk] = *(const ushort8*)(Bptr + k0);
        __syncthreads();
        bf16x8 af = *(const bf16x8*)&As[(wave * 16 + mr) * 32 + q * 8];
        #pragma unroll
        for (int j = 0; j < 4; j++) {
            bf16x8 bfr = *(const bf16x8*)&Bs[(j * 16 + mr) * 32 + q * 8];
            acc[j] = __builtin_amdgcn_mfma_f32_16x16x32_bf16(af, bfr, acc[j], 0, 0, 0);
        }
    }
    #pragma unroll
    for (int j = 0; j < 4; j++) {
        int gn = n0 + j * 16 + mr;          // d
        float cbv = cb[gn];
        #pragma unroll
        for (int r = 0; r < 4; r++) {
            int gm = wave * 16 + q * 4 + r; // e
            float v = acc[j][r] + rw[gm] * cbv + bE[(long)gm * D_MODEL + gn];
            unsigned short hi = f2bf(v);
            long tix = (long)gn * NUM_EXP + gm;
            oHi[tix] = hi;
            oLo[tix] = f2bf(v - bf2f(hi));
        }
    }
}

// ---------------- selector GEMM: 256x256 tile, 8-wave, 4-phase/K-tile pipelined ----------------
// Round-1 schedule (proven best) + 2 n-tiles per block (256 blocks = 1/CU, single
// dispatch round). Stage stream g is CONTINUOUS across the half boundary: the tail
// phases of half 0 prefetch half 1's first tiles (previously wasted clamped stages),
// so half 1's pipeline fill hides under half 0's compute/epilogue. vmcnt/lgkmcnt
// invariants identical to the single-pass version (g-index arithmetic unchanged).
// Mid-stream C-stores enter the vmcnt queue BEFORE later stages, so counted vmcnt(8)
// checks remain (conservatively) correct.
__launch_bounds__(512, 2)
__global__ void k_gemm_sel(const unsigned short* __restrict__ A,
                           const unsigned short* __restrict__ Bm,
                           const float* __restrict__ bias,
                           unsigned short* __restrict__ C)
{
    // [buf][khalf][256 rows][4 groups x 8 shorts], groups XOR-permuted per row-pair
    __shared__ __align__(16) unsigned short As[2][2][8192];
    __shared__ __align__(16) unsigned short Bs[2][2][8192];

    const int tid = threadIdx.x;
    const int wid = tid >> 6, lane = tid & 63;
    const int q = lane >> 4, mr = lane & 15;
    const int wm = wid >> 2, wn = wid & 3;           // 2x4 wave grid, 128x64 per wave
    const int kread = (q ^ ((mr >> 1) & 3)) * 8;

    // 256 blocks: 128 m-panels x 2 n-pairs; XCD-bijective (256 = 8 XCD x 32)
    const int bid = blockIdx.x;
    const int wg = (bid & 7) * 32 + (bid >> 3);
    const int m0 = (wg >> 1) * 256;
    const int npair = wg & 1;                        // n-tiles: npair*512 + h*256

    const unsigned short* Ag = A + (long)m0 * 1024;
    const unsigned short* Bg0 = Bm + (long)(npair * 512) * 1024;
    const unsigned short* Bg1 = Bg0 + (long)256 * 1024;

    // staging: slot s = j*512+tid -> row s>>2, phys group s&3 (j=1: row += 128, same key)
    const int srow = tid >> 2;
    const int sgrp = (tid & 3) ^ ((srow >> 1) & 3);
    const long soff = (long)srow * 1024 + sgrp * 8;
    const int ldst = wid * 64 * 8;                   // wave base (shorts) within region

    // continuous stage stream: slot g -> tile T=g>>2 (0..31 real, clamp), kh=(g>>1)&1,
    // operand isB=g&1. A restaged identically in half 1; B switches base at T>=16.
    auto STAGE = [&](int g) {
        int T = g >> 2; if (T > 31) T = 31;          // tail: redundant same-data re-stage
        const int kh = (g >> 1) & 1, isB = g & 1;
        const int tl = T & 15;
        const unsigned short* base = isB ? (T < 16 ? Bg0 : Bg1) : Ag;
        const unsigned short* src = base + (long)tl * 64 + kh * 32 + soff;
        unsigned short* dst = (isB ? &Bs[0][0][0] : &As[0][0][0])
                              + ((tl & 1) * 2 + kh) * 8192 + ldst;
        GLD16(src, dst);
        GLD16(src + 128 * 1024, dst + 4096);
    };

    floatx4 acc[8][4];
    floatx4 z4 = {0.f, 0.f, 0.f, 0.f};
    #pragma unroll
    for (int i = 0; i < 8; i++)
        #pragma unroll
        for (int j = 0; j < 4; j++) acc[i][j] = z4;

    // prologue: tile0 fully + tile1 kh0 (6 slots = 12 loads/thread in flight)
    STAGE(0); STAGE(1); STAGE(2); STAGE(3); STAGE(4); STAGE(5);
    asm volatile("s_waitcnt vmcnt(4)" ::: "memory");   // tile0 landed
    __builtin_amdgcn_s_barrier();

    for (int h = 0; h < 2; h++) {
        for (int t = 0; t < 16; t++) {
            const unsigned short* Abuf = &As[t & 1][0][0];
            const unsigned short* Bbuf = &Bs[t & 1][0][0];
            bf16x8 bfr[4];
            #pragma unroll
            for (int p = 0; p < 4; p++) {
                const int kh = p >> 1, mh = p & 1;
                bf16x8 af[4];
                #pragma unroll
                for (int i = 0; i < 4; i++)
                    af[i] = *(const bf16x8*)&Abuf[kh * 8192 +
                            (wm * 128 + mh * 64 + i * 16 + mr) * 32 + kread];
                if (mh == 0) {
                    #pragma unroll
                    for (int j = 0; j < 4; j++)
                        bfr[j] = *(const bf16x8*)&Bbuf[kh * 8192 +
                                 (wn * 64 + j * 16 + mr) * 32 + kread];
                }
                STAGE(h * 64 + 4 * t + p + 6);
                if (mh == 1) asm volatile("s_waitcnt vmcnt(8)" ::: "memory");
                __builtin_amdgcn_s_barrier();
                asm volatile("s_waitcnt lgkmcnt(0)" ::: "memory");
                __builtin_amdgcn_sched_barrier(0);
                __builtin_amdgcn_s_setprio(1);
                #pragma unroll
                for (int i = 0; i < 4; i++)
                    #pragma unroll
                    for (int j = 0; j < 4; j++)
                        acc[mh * 4 + i][j] = __builtin_amdgcn_mfma_f32_16x16x32_bf16(
                            af[i], bfr[j], acc[mh * 4 + i][j], 0, 0, 0);
                __builtin_amdgcn_s_setprio(0);
                __builtin_amdgcn_s_barrier();
                __builtin_amdgcn_sched_barrier(0);
            }
        }
        // epilogue for this n-half (no vmcnt drain: stream continues into half 1)
        const int n0 = npair * 512 + h * 256;
        #pragma unroll
        for (int i = 0; i < 8; i++) {
            #pragma unroll
            for (int j = 0; j < 4; j++) {
                const int gn = n0 + wn * 64 + j * 16 + mr;
                const float cbv = bias[gn];
                #pragma unroll
                for (int r = 0; r < 4; r++) {
                    const int gm = m0 + wm * 128 + i * 16 + q * 4 + r;
                    C[(long)gm * 1024 + gn] = f2bf(acc[i][j][r] + cbv);
                    if (h == 0) acc[i][j][r] = 0.f;
                }
            }
        }
    }
    asm volatile("s_waitcnt vmcnt(0)" ::: "memory");   // drain tail DMA before exit
}

// ---------------- fused norms: [0,1024) fwnorm (masked, over L) | [1024,1152) bwnorm (over E) ----------------
__global__ void k_norms(const float* __restrict__ z, const int* __restrict__ mask,
                        unsigned short* __restrict__ a_fw, unsigned short* __restrict__ b_fw,
                        float* __restrict__ wsum_a, float* __restrict__ wsum_b,
                        unsigned short* __restrict__ a_bw, unsigned short* __restrict__ b_bw)
{
    const int blk = blockIdx.x;
    const int tid = threadIdx.x;
    if (blk < 1024) {
        const int be = blk;
        const int b = be >> 6;
        const float* zr = z + (long)be * L_SZ;
        const int* mr = mask + (long)b * L_SZ;
        float sa = 0.f, sb = 0.f;
        for (int l = tid; l < L_SZ; l += 256) {
            float v = zr[l];
            if (mr[l] != 0) { sa += fmaxf(v, 0.f); sb += fmaxf(-v, 0.f); }
        }
        #pragma unroll
        for (int o = 32; o > 0; o >>= 1) { sa += __shfl_down(sa, o); sb += __shfl_down(sb, o); }
        __shared__ float red[8];
        int wave = tid >> 6, lane = tid & 63;
        if (lane == 0) { red[wave] = sa; red[4 + wave] = sb; }
        __syncthreads();
        float ta = red[0] + red[1] + red[2] + red[3];
        float tb = red[4] + red[5] + red[6] + red[7];
        float ia = 1.f / (ta + 1e-9f), ib = 1.f / (tb + 1e-9f);
        if (tid == 0) { wsum_a[be] = ta * ia; wsum_b[be] = tb * ib; }
        for (int l = tid; l < L_SZ; l += 256) {
            float v = zr[l];
            float m = (mr[l] != 0) ? 1.f : 0.f;
            a_fw[(long)be * L_SZ + l] = f2bf(fmaxf(v, 0.f) * m * ia);
            b_fw[(long)be * L_SZ + l] = f2bf(fmaxf(-v, 0.f) * m * ib);
        }
    } else {
        int r = (blk - 1024) * 256 + tid;
        int b = r >> 11, l = r & 2047;
        const float* zb = z + (long)b * NUM_EXP * L_SZ + l;
        float sa = 0.f, sb = 0.f;
        float va[NUM_EXP];
        #pragma unroll 8
        for (int e = 0; e < NUM_EXP; e++) {
            float v = zb[(long)e * L_SZ];
            va[e] = v;
            sa += fmaxf(v, 0.f); sb += fmaxf(-v, 0.f);
        }
        float ia = 1.f / (sa + 1e-9f), ib = 1.f / (sb + 1e-9f);
        unsigned short* ar = a_bw + (long)r * NUM_EXP;
        unsigned short* br = b_bw + (long)r * NUM_EXP;
        #pragma unroll 8
        for (int e = 0; e < NUM_EXP; e++) {
            float v = va[e];
            ar[e] = f2bf(fmaxf(v, 0.f) * ia);
            br[e] = f2bf(fmaxf(-v, 0.f) * ib);
        }
    }
}

// ---------------- final: out = sig(sel)*(aw@clsA) + (1-sig)*(bw@clsB) via MFMA ----------------
__launch_bounds__(256)
__global__ void k_final_mfma(const unsigned short* __restrict__ aw,
                             const unsigned short* __restrict__ bw,
                             const unsigned short* __restrict__ caHi,
                             const unsigned short* __restrict__ caLo,
                             const unsigned short* __restrict__ cbHi,
                             const unsigned short* __restrict__ cbLo,
                             const unsigned short* __restrict__ selbf,   // bf16 logits
                             float* __restrict__ out)
{
    __shared__ __align__(16) unsigned short Aa[64 * 72];
    __shared__ __align__(16) unsigned short Ab[64 * 72];
    __shared__ __align__(16) unsigned short BaH[64 * 72];
    __shared__ __align__(16) unsigned short BaL[64 * 72];
    __shared__ __align__(16) unsigned short BbH[64 * 72];
    __shared__ __align__(16) unsigned short BbL[64 * 72];
    const int bz = blockIdx.z;
    const int l0 = blockIdx.y * 64, d0 = blockIdx.x * 64;
    const int tid = threadIdx.x;
    const int wave = tid >> 6, lane = tid & 63;
    const int q = lane >> 4, mr = lane & 15;

    const unsigned short* awb = aw + ((long)bz * L_SZ + l0) * NUM_EXP;
    const unsigned short* bwb = bw + ((long)bz * L_SZ + l0) * NUM_EXP;
    const long cbase = ((long)bz * D_MODEL + d0) * NUM_EXP;

    #pragma unroll
    for (int c = 0; c < 2; c++) {
        int idx = c * 256 + tid;
        int row = idx >> 3, kc = (idx & 7) * 8;
        int lw = row * 72 + kc;
        long ga = (long)row * NUM_EXP + kc;
        *(ushort8*)&Aa[lw]  = *(const ushort8*)(awb + ga);
        *(ushort8*)&Ab[lw]  = *(const ushort8*)(bwb + ga);
        *(ushort8*)&BaH[lw] = *(const ushort8*)(caHi + cbase + ga);
        *(ushort8*)&BaL[lw] = *(const ushort8*)(caLo + cbase + ga);
        *(ushort8*)&BbH[lw] = *(const ushort8*)(cbHi + cbase + ga);
        *(ushort8*)&BbL[lw] = *(const ushort8*)(cbLo + cbase + ga);
    }
    __syncthreads();

    floatx4 accA[4], accB[4];
    floatx4 z4 = {0.f, 0.f, 0.f, 0.f};
    #pragma unroll
    for (int j = 0; j < 4; j++) { accA[j] = z4; accB[j] = z4; }

    #pragma unroll
    for (int ks = 0; ks < 2; ks++) {
        int ko = ks * 32 + q * 8;
        bf16x8 fa = *(const bf16x8*)&Aa[(wave * 16 + mr) * 72 + ko];
        bf16x8 fb = *(const bf16x8*)&Ab[(wave * 16 + mr) * 72 + ko];
        #pragma unroll
        for (int j = 0; j < 4; j++) {
            int bo = (j * 16 + mr) * 72 + ko;
            accA[j] = __builtin_amdgcn_mfma_f32_16x16x32_bf16(fa, *(const bf16x8*)&BaH[bo], accA[j], 0, 0, 0);
            accA[j] = __builtin_amdgcn_mfma_f32_16x16x32_bf16(fa, *(const bf16x8*)&BaL[bo], accA[j], 0, 0, 0);
            accB[j] = __builtin_amdgcn_mfma_f32_16x16x32_bf16(fb, *(const bf16x8*)&BbH[bo], accB[j], 0, 0, 0);
            accB[j] = __builtin_amdgcn_mfma_f32_16x16x32_bf16(fb, *(const bf16x8*)&BbL[bo], accB[j], 0, 0, 0);
        }
    }

    #pragma unroll
    for (int j = 0; j < 4; j++) {
        #pragma unroll
        for (int r = 0; r < 4; r++) {
            int gl = l0 + wave * 16 + q * 4 + r;
            int gd = d0 + j * 16 + mr;
            long o = ((long)bz * L_SZ + gl) * D_MODEL + gd;
            float s = 1.f / (1.f + __expf(-bf2f(selbf[o])));
            out[o] = s * accA[j][r] + (1.f - s) * accB[j][r];
        }
    }
}

extern "C" void kernel_launch(void* const* d_in, const int* in_sizes, int n_in,
                              void* d_out, int out_size, void* d_ws, size_t ws_size,
                              hipStream_t stream)
{
    const float* x     = (const float*)d_in[0];
    const int*   nidx  = (const int*)d_in[1];
    const int*   mask  = (const int*)d_in[2];
    const float* q_emb = (const float*)d_in[3];
    const float* b_emb = (const float*)d_in[4];
    const float* Wk    = (const float*)d_in[5];
    const float* bk    = (const float*)d_in[6];
    const float* Wa    = (const float*)d_in[7];
    const float* ba    = (const float*)d_in[8];
    const float* Wb    = (const float*)d_in[9];
    const float* bb    = (const float*)d_in[10];
    const float* Ws    = (const float*)d_in[11];
    const float* bs    = (const float*)d_in[12];
    float* out = (float*)d_out;

    constexpr long BLD = (long)B_SZ * L_SZ * D_MODEL;
    constexpr long BEL = (long)B_SZ * NUM_EXP * L_SZ;
    constexpr long BED = (long)B_SZ * NUM_EXP * D_MODEL;
    constexpr long DD  = (long)D_MODEL * D_MODEL;

    char* w = (char*)d_ws;
    size_t off = 0;
    auto carve = [&](size_t bytes) { char* p = w + off; off += (bytes + 255) & ~(size_t)255; return p; };
    unsigned short* x_bf   = (unsigned short*)carve(BLD * 2);
    unsigned short* x_bfT  = (unsigned short*)carve(BLD * 2);  // later reused as sel logits
    unsigned short* wkT_bf = (unsigned short*)carve(DD * 2);
    unsigned short* wa_bf  = (unsigned short*)carve(DD * 2);
    unsigned short* wb_bf  = (unsigned short*)carve(DD * 2);
    unsigned short* ws_bf  = (unsigned short*)carve(DD * 2);
    unsigned short* qexp   = (unsigned short*)carve(BED * 2);
    float*          bias_e = (float*)carve(BED * 4);
    float*          qbk    = (float*)carve(B_SZ * NUM_EXP * 4);
    unsigned short* qk     = (unsigned short*)carve(BED * 2);
    float*          z      = (float*)carve(BEL * 4);
    unsigned short* a_fw   = (unsigned short*)carve(BEL * 2);
    unsigned short* b_fw   = (unsigned short*)carve(BEL * 2);
    float*          wsum_a = (float*)carve(B_SZ * NUM_EXP * 4);
    float*          wsum_b = (float*)carve(B_SZ * NUM_EXP * 4);
    unsigned short* a_bw   = (unsigned short*)carve(BEL * 2);
    unsigned short* b_bw   = (unsigned short*)carve(BEL * 2);
    unsigned short* fwx_a  = (unsigned short*)carve(BED * 2);
    unsigned short* fwx_b  = (unsigned short*)carve(BED * 2);
    unsigned short* caHi   = (unsigned short*)carve(BED * 2);
    unsigned short* caLo   = (unsigned short*)carve(BED * 2);
    unsigned short* cbHi   = (unsigned short*)carve(BED * 2);
    unsigned short* cbLo   = (unsigned short*)carve(BED * 2);
    if (ws_size < off) return;
    unsigned short* selbf = x_bfT;  // x_bfT dead after fw2 GEMM; sel GEMM runs after it

    // 1. conversions / transposes / gather (fused prep)
    k_convx<<<dim3(16, 32, B_SZ), 256, 0, stream>>>(x, x_bf, x_bfT);
    k_prep<<<2816, 256, 0, stream>>>(Wk, Wa, Wb, Ws, nidx, q_emb, b_emb, bk,
                                     wkT_bf, wa_bf, wb_bf, ws_bf, qexp, bias_e, qbk);

    // 2. qk[e,n] = sum_d qexp[e,d] * WkT[n,d]   (bf16 out)
    k_gemm_bt<<<dim3(16, 1, B_SZ), 256, 0, stream>>>(qexp, wkT_bf, nullptr, qk,
        NUM_EXP, D_MODEL, D_MODEL, 1.f, 1, (long)NUM_EXP * D_MODEL, 0, (long)NUM_EXP * D_MODEL);

    // 3. z[e,l] = (qk[e,:]·x[l,:] + qbk[e]) / 32  (f32)
    k_gemm_bt<<<dim3(32, 1, B_SZ), 256, 0, stream>>>(qk, x_bf, qbk, z,
        NUM_EXP, L_SZ, D_MODEL, 1.f / 32.f, 0,
        (long)NUM_EXP * D_MODEL, (long)L_SZ * D_MODEL, (long)NUM_EXP * L_SZ);

    // 4. normalizations (fused fw+bw)
    k_norms<<<1152, 256, 0, stream>>>(z, mask, a_fw, b_fw, wsum_a, wsum_b, a_bw, b_bw);

    // 5. fwx_{a,b}[e,c] = sum_l fw[e,l]·xT[c,l]  (fused, shared B; 512 thr, K-split x2)
    k_gemm_fw2<<<dim3(16, 1, B_SZ), 512, 0, stream>>>(a_fw, b_fw, x_bfT, fwx_a, fwx_b);

    // 6. sel logits -> selbf (aliases x_bfT; runs AFTER fw2). 256 blocks x 2 n-tiles.
    k_gemm_sel<<<256, 512, 0, stream>>>(x_bf, ws_bf, bs, selbf);

    // 7. cls (both sides fused), transposed split store
    k_gemm_cls<<<dim3(16, 1, 32), 256, 0, stream>>>(fwx_a, fwx_b, wa_bf, wb_bf, ba, bb,
        wsum_a, wsum_b, bias_e, caHi, caLo, cbHi, cbLo);

    // 8. final blend
    k_final_mfma<<<dim3(16, 32, B_SZ), 256, 0, stream>>>(a_bw, b_bw, caHi, caLo, cbHi, cbLo, selbf, out);
}

// Round 5
// 506.773 us; speedup vs baseline: 1.0822x; 1.0333x over previous
//
#include <hip/hip_runtime.h>
#include <math.h>

#define D_MODEL 1024
#define NUM_EXP 64
#define B_SZ 16
#define L_SZ 2048

using bf16x8  = __attribute__((ext_vector_type(8))) __bf16;
using floatx4 = __attribute__((ext_vector_type(4))) float;
using ushort8 = __attribute__((ext_vector_type(8))) unsigned short;
using ushort4v = __attribute__((ext_vector_type(4))) unsigned short;

__device__ __forceinline__ unsigned short f2bf(float f) {
    union { float f; unsigned u; } x; x.f = f;
    unsigned r = (x.u + 0x7fffu + ((x.u >> 16) & 1u)) >> 16;
    return (unsigned short)r;
}
__device__ __forceinline__ float bf2f(unsigned short h) {
    union { unsigned u; float f; } x; x.u = ((unsigned)h) << 16;
    return x.f;
}

// async 16B global->LDS (lds base wave-uniform; lane i lands at base+16*i)
#define GLD16(gp, lp) __builtin_amdgcn_global_load_lds( \
    (const __attribute__((address_space(1))) unsigned int*)(gp), \
    (__attribute__((address_space(3))) unsigned int*)(lp), 16, 0, 0)

// ---------------- x: f32 -> bf16, both [B,L,D] and transposed [B,D,L] ----------------
__global__ void k_convx(const float* __restrict__ in, unsigned short* __restrict__ outN,
                        unsigned short* __restrict__ outT)
{
    __shared__ unsigned short T[64][65];
    const int b = blockIdx.z;
    const int l0 = blockIdx.y * 64, c0 = blockIdx.x * 64;
    const int t = threadIdx.x;
    const int tr = t >> 4, tc = (t & 15) * 4;
    const float* src = in + ((long)b * L_SZ + l0) * D_MODEL + c0;
    unsigned short* dN = outN + ((long)b * L_SZ + l0) * D_MODEL + c0;
    #pragma unroll
    for (int i = 0; i < 4; i++) {
        int r = tr + i * 16;
        float4 v = *(const float4*)(src + (long)r * D_MODEL + tc);
        ushort4v u; u[0]=f2bf(v.x); u[1]=f2bf(v.y); u[2]=f2bf(v.z); u[3]=f2bf(v.w);
        *(ushort4v*)(dN + (long)r * D_MODEL + tc) = u;
        T[r][tc+0]=u[0]; T[r][tc+1]=u[1]; T[r][tc+2]=u[2]; T[r][tc+3]=u[3];
    }
    __syncthreads();
    unsigned short* dT = outT + ((long)b * D_MODEL + c0) * L_SZ + l0;
    #pragma unroll
    for (int i = 0; i < 4; i++) {
        int c = tr + i * 16;
        ushort4v u;
        u[0]=T[tc+0][c]; u[1]=T[tc+1][c]; u[2]=T[tc+2][c]; u[3]=T[tc+3][c];
        *(ushort4v*)(dT + (long)c * L_SZ + tc) = u;
    }
}

// ---------------- fused prep: [0,256) Wk transpose | [256,1792) Wa/Wb/Ws conv | [1792,2816) gather ----------------
__global__ void k_prep(const float* __restrict__ Wk,
                       const float* __restrict__ Wa, const float* __restrict__ Wb,
                       const float* __restrict__ Ws,
                       const int* __restrict__ idx, const float* __restrict__ q_emb,
                       const float* __restrict__ b_emb, const float* __restrict__ bk,
                       unsigned short* __restrict__ wkT,
                       unsigned short* __restrict__ oa, unsigned short* __restrict__ ob,
                       unsigned short* __restrict__ oc,
                       unsigned short* __restrict__ qexp, float* __restrict__ bias_exp,
                       float* __restrict__ qbk)
{
    __shared__ unsigned short T[64][65];
    __shared__ float red[4];
    const int blk = blockIdx.x;
    const int t = threadIdx.x;
    if (blk < 256) {
        const int r0 = (blk >> 4) * 64, c0 = (blk & 15) * 64;
        const int tr = t >> 4, tc = (t & 15) * 4;
        const float* src = Wk + (long)r0 * D_MODEL + c0;
        #pragma unroll
        for (int i = 0; i < 4; i++) {
            int r = tr + i * 16;
            float4 v = *(const float4*)(src + (long)r * D_MODEL + tc);
            T[r][tc+0]=f2bf(v.x); T[r][tc+1]=f2bf(v.y); T[r][tc+2]=f2bf(v.z); T[r][tc+3]=f2bf(v.w);
        }
        __syncthreads();
        unsigned short* dT = wkT + ((long)c0) * D_MODEL + r0;
        #pragma unroll
        for (int i = 0; i < 4; i++) {
            int c = tr + i * 16;
            ushort4v u;
            u[0]=T[tc+0][c]; u[1]=T[tc+1][c]; u[2]=T[tc+2][c]; u[3]=T[tc+3][c];
            *(ushort4v*)(dT + (long)c * D_MODEL + tc) = u;
        }
    } else if (blk < 256 + 1536) {
        long i = ((long)(blk - 256) * 256 + t) * 8;
        int which = (int)(i >> 20);
        long off = i & ((1L << 20) - 1);
        const float* src = which == 0 ? Wa : which == 1 ? Wb : Ws;
        unsigned short* dst = which == 0 ? oa : which == 1 ? ob : oc;
        float4 v0 = *(const float4*)(src + off);
        float4 v1 = *(const float4*)(src + off + 4);
        ushort8 r;
        r[0]=f2bf(v0.x); r[1]=f2bf(v0.y); r[2]=f2bf(v0.z); r[3]=f2bf(v0.w);
        r[4]=f2bf(v1.x); r[5]=f2bf(v1.y); r[6]=f2bf(v1.z); r[7]=f2bf(v1.w);
        *(ushort8*)(dst + off) = r;
    } else {
        const int be = blk - 1792;
        const int row = idx[be];
        const float* qs = q_emb + (long)row * D_MODEL;
        const float* bsrc = b_emb + (long)row * D_MODEL;
        float4 q4 = *(const float4*)(qs + t * 4);
        float4 k4 = *(const float4*)(bk + t * 4);
        float4 b4 = *(const float4*)(bsrc + t * 4);
        ushort4v r; r[0]=f2bf(q4.x); r[1]=f2bf(q4.y); r[2]=f2bf(q4.z); r[3]=f2bf(q4.w);
        *(ushort4v*)(qexp + (long)be * D_MODEL + t * 4) = r;
        *(float4*)(bias_exp + (long)be * D_MODEL + t * 4) = b4;
        float p = q4.x*k4.x + q4.y*k4.y + q4.z*k4.z + q4.w*k4.w;
        #pragma unroll
        for (int o = 32; o > 0; o >>= 1) p += __shfl_down(p, o);
        if ((t & 63) == 0) red[t >> 6] = p;
        __syncthreads();
        if (t == 0) qbk[be] = red[0] + red[1] + red[2] + red[3];
    }
}

// ---------------- qk64: qk[e,n] = sum_d qexp[e,d]*WkT[n,d], bf16 out ----------------
// M=64; 512 threads = two 4-wave groups K-splitting (2 waves/SIMD, 16 steps each)
__launch_bounds__(512)
__global__ void k_gemm_qk64(const unsigned short* __restrict__ qexp,
                            const unsigned short* __restrict__ WkT,
                            unsigned short* __restrict__ Cq)
{
    __shared__ __align__(16) unsigned short As[2][64 * 32];
    __shared__ __align__(16) unsigned short Bs2[2][64 * 32];
    __shared__ float Red[64][65];
    const int bz = blockIdx.z, n0 = blockIdx.x * 64;
    const int tid = threadIdx.x;
    const int grp = tid >> 8, gtid = tid & 255;
    const int wave = gtid >> 6, lane = tid & 63;
    const int lrow = gtid >> 2, lk = (gtid & 3) * 8;
    const int q = lane >> 4, mr = lane & 15;
    const int kb = grp * (D_MODEL / 2);

    const unsigned short* Ap = qexp + ((long)bz * NUM_EXP + lrow) * D_MODEL + kb + lk;
    const unsigned short* Bp = WkT + (long)(n0 + lrow) * D_MODEL + kb + lk;

    floatx4 acc[4];
    floatx4 z4 = {0.f, 0.f, 0.f, 0.f};
    #pragma unroll
    for (int j = 0; j < 4; j++) acc[j] = z4;

    for (int k0 = 0; k0 < D_MODEL / 2; k0 += 32) {
        __syncthreads();
        *(ushort8*)&As[grp][lrow * 32 + lk] = *(const ushort8*)(Ap + k0);
        *(ushort8*)&Bs2[grp][lrow * 32 + lk] = *(const ushort8*)(Bp + k0);
        __syncthreads();
        bf16x8 af = *(const bf16x8*)&As[grp][(wave * 16 + mr) * 32 + q * 8];
        #pragma unroll
        for (int j = 0; j < 4; j++) {
            bf16x8 bfr = *(const bf16x8*)&Bs2[grp][(j * 16 + mr) * 32 + q * 8];
            acc[j] = __builtin_amdgcn_mfma_f32_16x16x32_bf16(af, bfr, acc[j], 0, 0, 0);
        }
    }
    __syncthreads();
    if (grp == 1) {
        #pragma unroll
        for (int j = 0; j < 4; j++)
            #pragma unroll
            for (int r = 0; r < 4; r++)
                Red[wave * 16 + q * 4 + r][j * 16 + mr] = acc[j][r];
    }
    __syncthreads();
    if (grp == 0) {
        #pragma unroll
        for (int j = 0; j < 4; j++) {
            int gn = n0 + j * 16 + mr;
            #pragma unroll
            for (int r = 0; r < 4; r++) {
                int gm = wave * 16 + q * 4 + r;
                Cq[((long)bz * NUM_EXP + gm) * D_MODEL + gn] =
                    f2bf(acc[j][r] + Red[gm][j * 16 + mr]);
            }
        }
    }
}

// ---------------- z GEMM + fused bw-norm ----------------
// z[e,l] = (qk[e,:]·x[l,:] + qbk[e])/32 (f32 out). Since M = NUM_EXP = 64, each block
// holds ALL e for its l-columns -> compute a_bw/b_bw (norm over e) in the epilogue.
__launch_bounds__(512)
__global__ void k_gemm_z(const unsigned short* __restrict__ qk,
                         const unsigned short* __restrict__ x_bf,
                         const float* __restrict__ qbk,
                         float* __restrict__ z,
                         unsigned short* __restrict__ a_bw,
                         unsigned short* __restrict__ b_bw)
{
    __shared__ __align__(16) unsigned short As[2][64 * 32];
    __shared__ __align__(16) unsigned short Bs2[2][64 * 32];
    __shared__ float Red[64][65];
    const int bz = blockIdx.z, n0 = blockIdx.x * 64;
    const int tid = threadIdx.x;
    const int grp = tid >> 8, gtid = tid & 255;
    const int wave = gtid >> 6, lane = tid & 63;
    const int lrow = gtid >> 2, lk = (gtid & 3) * 8;
    const int q = lane >> 4, mr = lane & 15;
    const int kb = grp * (D_MODEL / 2);

    const unsigned short* Ap = qk + ((long)bz * NUM_EXP + lrow) * D_MODEL + kb + lk;
    const unsigned short* Bp = x_bf + ((long)bz * L_SZ + n0 + lrow) * D_MODEL + kb + lk;

    floatx4 acc[4];
    floatx4 z4 = {0.f, 0.f, 0.f, 0.f};
    #pragma unroll
    for (int j = 0; j < 4; j++) acc[j] = z4;

    for (int k0 = 0; k0 < D_MODEL / 2; k0 += 32) {
        __syncthreads();
        *(ushort8*)&As[grp][lrow * 32 + lk] = *(const ushort8*)(Ap + k0);
        *(ushort8*)&Bs2[grp][lrow * 32 + lk] = *(const ushort8*)(Bp + k0);
        __syncthreads();
        bf16x8 af = *(const bf16x8*)&As[grp][(wave * 16 + mr) * 32 + q * 8];
        #pragma unroll
        for (int j = 0; j < 4; j++) {
            bf16x8 bfr = *(const bf16x8*)&Bs2[grp][(j * 16 + mr) * 32 + q * 8];
            acc[j] = __builtin_amdgcn_mfma_f32_16x16x32_bf16(af, bfr, acc[j], 0, 0, 0);
        }
    }
    __syncthreads();
    if (grp == 1) {
        #pragma unroll
        for (int j = 0; j < 4; j++)
            #pragma unroll
            for (int r = 0; r < 4; r++)
                Red[wave * 16 + q * 4 + r][j * 16 + mr] = acc[j][r];
    }
    __syncthreads();
    if (grp == 0) {
        #pragma unroll
        for (int j = 0; j < 4; j++) {
            int gn = n0 + j * 16 + mr;          // l
            #pragma unroll
            for (int r = 0; r < 4; r++) {
                int gm = wave * 16 + q * 4 + r; // e
                float v = (acc[j][r] + Red[gm][j * 16 + mr] + qbk[bz * NUM_EXP + gm]) * (1.f / 32.f);
                z[((long)bz * NUM_EXP + gm) * L_SZ + gn] = v;
                Red[gm][j * 16 + mr] = v;       // thread-local RMW, same slot
            }
        }
    }
    __syncthreads();
    // bw-norm over e for each l-column (64 columns, one thread each)
    if (tid < 64) {
        const int l = n0 + tid;
        float sa = 0.f, sb = 0.f;
        #pragma unroll
        for (int e = 0; e < NUM_EXP; e++) {
            float v = Red[e][tid];
            sa += fmaxf(v, 0.f); sb += fmaxf(-v, 0.f);
        }
        float ia = 1.f / (sa + 1e-9f), ib = 1.f / (sb + 1e-9f);
        unsigned short* ar = a_bw + ((long)bz * L_SZ + l) * NUM_EXP;
        unsigned short* br = b_bw + ((long)bz * L_SZ + l) * NUM_EXP;
        #pragma unroll
        for (int eo = 0; eo < NUM_EXP; eo += 8) {
            ushort8 ra, rb;
            #pragma unroll
            for (int k = 0; k < 8; k++) {
                float v = Red[eo + k][tid];
                ra[k] = f2bf(fmaxf(v, 0.f) * ia);
                rb[k] = f2bf(fmaxf(-v, 0.f) * ib);
            }
            *(ushort8*)(ar + eo) = ra;
            *(ushort8*)(br + eo) = rb;
        }
    }
}

// ---------------- fused fwx GEMM (bt): C1=A1@Bt^T, C2=A2@Bt^T, shared B ----------------
__launch_bounds__(512)
__global__ void k_gemm_fw2(const unsigned short* __restrict__ A1,   // a_fw [B,64,L]
                           const unsigned short* __restrict__ A2,   // b_fw
                           const unsigned short* __restrict__ Bt,   // x_bfT [B,D,L]
                           unsigned short* __restrict__ C1,         // fwx_a [B,64,D]
                           unsigned short* __restrict__ C2)
{
    __shared__ __align__(16) unsigned short As1[2][64 * 32];
    __shared__ __align__(16) unsigned short As2[2][64 * 32];
    __shared__ __align__(16) unsigned short Bs[2][64 * 32];
    __shared__ float Red[2][64][65];
    const int bz = blockIdx.z;
    const int n0 = blockIdx.x * 64;
    const int tid = threadIdx.x;
    const int grp = tid >> 8;
    const int gtid = tid & 255;
    const int wave = gtid >> 6, lane = tid & 63;
    const int lrow = gtid >> 2, lk = (gtid & 3) * 8;
    const int q = lane >> 4, mr = lane & 15;
    const int kb = grp * (L_SZ / 2);

    const unsigned short* a1p = A1 + ((long)bz * NUM_EXP + lrow) * L_SZ + kb + lk;
    const unsigned short* a2p = A2 + ((long)bz * NUM_EXP + lrow) * L_SZ + kb + lk;
    const unsigned short* bp  = Bt + ((long)bz * D_MODEL + n0 + lrow) * L_SZ + kb + lk;

    floatx4 acc1[4], acc2[4];
    floatx4 z4 = {0.f, 0.f, 0.f, 0.f};
    #pragma unroll
    for (int j = 0; j < 4; j++) { acc1[j] = z4; acc2[j] = z4; }

    for (int k0 = 0; k0 < L_SZ / 2; k0 += 32) {
        __syncthreads();
        *(ushort8*)&As1[grp][lrow * 32 + lk] = *(const ushort8*)(a1p + k0);
        *(ushort8*)&As2[grp][lrow * 32 + lk] = *(const ushort8*)(a2p + k0);
        *(ushort8*)&Bs[grp][lrow * 32 + lk]  = *(const ushort8*)(bp + k0);
        __syncthreads();
        bf16x8 f1 = *(const bf16x8*)&As1[grp][(wave * 16 + mr) * 32 + q * 8];
        bf16x8 f2 = *(const bf16x8*)&As2[grp][(wave * 16 + mr) * 32 + q * 8];
        #pragma unroll
        for (int j = 0; j < 4; j++) {
            bf16x8 bb = *(const bf16x8*)&Bs[grp][(j * 16 + mr) * 32 + q * 8];
            acc1[j] = __builtin_amdgcn_mfma_f32_16x16x32_bf16(f1, bb, acc1[j], 0, 0, 0);
            acc2[j] = __builtin_amdgcn_mfma_f32_16x16x32_bf16(f2, bb, acc2[j], 0, 0, 0);
        }
    }
    __syncthreads();
    if (grp == 1) {
        #pragma unroll
        for (int j = 0; j < 4; j++)
            #pragma unroll
            for (int r = 0; r < 4; r++) {
                int gm = wave * 16 + q * 4 + r;
                Red[0][gm][j * 16 + mr] = acc1[j][r];
                Red[1][gm][j * 16 + mr] = acc2[j][r];
            }
    }
    __syncthreads();
    if (grp == 0) {
        #pragma unroll
        for (int j = 0; j < 4; j++) {
            int gn = n0 + j * 16 + mr;
            #pragma unroll
            for (int r = 0; r < 4; r++) {
                int gm = wave * 16 + q * 4 + r;
                long cidx = ((long)bz * NUM_EXP + gm) * D_MODEL + gn;
                C1[cidx] = f2bf(acc1[j][r] + Red[0][gm][j * 16 + mr]);
                C2[cidx] = f2bf(acc2[j][r] + Red[1][gm][j * 16 + mr]);
            }
        }
    }
}

// ---------------- cls64: K-split x2; side = blockIdx.z>>4 ----------------
// cls[e,d] = fwx[e,:]·W[d,:] + wsum[e]*bias[d] + biasE[e,d]; split hi/lo, transposed [d,e]
__launch_bounds__(512)
__global__ void k_gemm_cls64(const unsigned short* __restrict__ fwxA, const unsigned short* __restrict__ fwxB,
                             const unsigned short* __restrict__ Wa_, const unsigned short* __restrict__ Wb_,
                             const float* __restrict__ ba_, const float* __restrict__ bb_,
                             const float* __restrict__ wsA, const float* __restrict__ wsB,
                             const float* __restrict__ biasE,
                             unsigned short* __restrict__ aHi, unsigned short* __restrict__ aLo,
                             unsigned short* __restrict__ bHi, unsigned short* __restrict__ bLo)
{
    __shared__ __align__(16) unsigned short As[2][64 * 32];
    __shared__ __align__(16) unsigned short Bs2[2][64 * 32];
    __shared__ float Red[64][65];
    const int zz = blockIdx.z;
    const int side = zz >> 4, bz = zz & 15;
    const unsigned short* Ab = (side ? fwxB : fwxA) + (long)bz * NUM_EXP * D_MODEL;
    const unsigned short* Bb = side ? Wb_ : Wa_;
    const float* cb = side ? bb_ : ba_;
    const float* rw = (side ? wsB : wsA) + bz * NUM_EXP;
    const float* bE = biasE + (long)bz * NUM_EXP * D_MODEL;
    unsigned short* oHi = (side ? bHi : aHi) + (long)bz * NUM_EXP * D_MODEL;
    unsigned short* oLo = (side ? bLo : aLo) + (long)bz * NUM_EXP * D_MODEL;

    const int tid = threadIdx.x;
    const int grp = tid >> 8, gtid = tid & 255;
    const int wave = gtid >> 6, lane = tid & 63;
    const int n0 = blockIdx.x * 64;
    const int lrow = gtid >> 2, lk = (gtid & 3) * 8;
    const int q = lane >> 4, mr = lane & 15;
    const int kb = grp * (D_MODEL / 2);

    floatx4 acc[4];
    floatx4 z4 = {0.f, 0.f, 0.f, 0.f};
    #pragma unroll
    for (int j = 0; j < 4; j++) acc[j] = z4;

    const unsigned short* Aptr = Ab + (long)lrow * D_MODEL + kb + lk;
    const unsigned short* Bptr = Bb + (long)(n0 + lrow) * D_MODEL + kb + lk;

    for (int k0 = 0; k0 < D_MODEL / 2; k0 += 32) {
        __syncthreads();
        *(ushort8*)&As[grp][lrow * 32 + lk] = *(const ushort8*)(Aptr + k0);
        *(ushort8*)&Bs2[grp][lrow * 32 + lk] = *(const ushort8*)(Bptr + k0);
        __syncthreads();
        bf16x8 af = *(const bf16x8*)&As[grp][(wave * 16 + mr) * 32 + q * 8];
        #pragma unroll
        for (int j = 0; j < 4; j++) {
            bf16x8 bfr = *(const bf16x8*)&Bs2[grp][(j * 16 + mr) * 32 + q * 8];
            acc[j] = __builtin_amdgcn_mfma_f32_16x16x32_bf16(af, bfr, acc[j], 0, 0, 0);
        }
    }
    __syncthreads();
    if (grp == 1) {
        #pragma unroll
        for (int j = 0; j < 4; j++)
            #pragma unroll
            for (int r = 0; r < 4; r++)
                Red[wave * 16 + q * 4 + r][j * 16 + mr] = acc[j][r];
    }
    __syncthreads();
    if (grp == 0) {
        #pragma unroll
        for (int j = 0; j < 4; j++) {
            int gn = n0 + j * 16 + mr;          // d
            float cbv = cb[gn];
            #pragma unroll
            for (int r = 0; r < 4; r++) {
                int gm = wave * 16 + q * 4 + r; // e
                float v = acc[j][r] + Red[gm][j * 16 + mr] + rw[gm] * cbv
                          + bE[(long)gm * D_MODEL + gn];
                unsigned short hi = f2bf(v);
                long tix = (long)gn * NUM_EXP + gm;
                oHi[tix] = hi;
                oLo[tix] = f2bf(v - bf2f(hi));
            }
        }
    }
}

// ---------------- selector GEMM: 256x256 tile, 8-wave, 4-phase/K-tile pipelined ----------------
// Round-1 proven schedule: counted vmcnt across raw barriers, XOR-swizzled LDS,
// setprio around MFMA cluster, 512 blocks (XCD-bijective).
__launch_bounds__(512, 2)
__global__ void k_gemm_sel(const unsigned short* __restrict__ A,
                           const unsigned short* __restrict__ Bm,
                           const float* __restrict__ bias,
                           unsigned short* __restrict__ C)
{
    __shared__ __align__(16) unsigned short As[2][2][8192];
    __shared__ __align__(16) unsigned short Bs[2][2][8192];

    const int tid = threadIdx.x;
    const int wid = tid >> 6, lane = tid & 63;
    const int q = lane >> 4, mr = lane & 15;
    const int wm = wid >> 2, wn = wid & 3;           // 2x4 wave grid, 128x64 per wave
    const int kread = (q ^ ((mr >> 1) & 3)) * 8;

    const int bid = blockIdx.x;
    const int wg = (bid & 7) * 64 + (bid >> 3);
    const int m0 = (wg >> 2) * 256;
    const int n0 = (wg & 3) * 256;

    const unsigned short* Ag = A + (long)m0 * 1024;
    const unsigned short* Bg = Bm + (long)n0 * 1024;

    const int srow = tid >> 2;
    const int sgrp = (tid & 3) ^ ((srow >> 1) & 3);
    const long soff = (long)srow * 1024 + sgrp * 8;
    const int ldst = wid * 64 * 8;

    auto STAGE = [&](int g) {
        int tile = g >> 2; if (tile > 15) tile = 15;
        const int kh = (g >> 1) & 1, isB = g & 1;
        const unsigned short* src = (isB ? Bg : Ag) + (long)tile * 64 + kh * 32 + soff;
        unsigned short* dst = (isB ? &Bs[0][0][0] : &As[0][0][0])
                              + ((tile & 1) * 2 + kh) * 8192 + ldst;
        GLD16(src, dst);
        GLD16(src + 128 * 1024, dst + 4096);
    };

    floatx4 acc[8][4];
    floatx4 z4 = {0.f, 0.f, 0.f, 0.f};
    #pragma unroll
    for (int i = 0; i < 8; i++)
        #pragma unroll
        for (int j = 0; j < 4; j++) acc[i][j] = z4;

    STAGE(0); STAGE(1); STAGE(2); STAGE(3); STAGE(4); STAGE(5);
    asm volatile("s_waitcnt vmcnt(4)" ::: "memory");
    __builtin_amdgcn_s_barrier();

    for (int t = 0; t < 16; t++) {
        const unsigned short* Abuf = &As[t & 1][0][0];
        const unsigned short* Bbuf = &Bs[t & 1][0][0];
        bf16x8 bfr[4];
        #pragma unroll
        for (int p = 0; p < 4; p++) {
            const int kh = p >> 1, mh = p & 1;
            bf16x8 af[4];
            #pragma unroll
            for (int i = 0; i < 4; i++)
                af[i] = *(const bf16x8*)&Abuf[kh * 8192 +
                        (wm * 128 + mh * 64 + i * 16 + mr) * 32 + kread];
            if (mh == 0) {
                #pragma unroll
                for (int j = 0; j < 4; j++)
                    bfr[j] = *(const bf16x8*)&Bbuf[kh * 8192 +
                             (wn * 64 + j * 16 + mr) * 32 + kread];
            }
            STAGE(4 * t + p + 6);
            if (mh == 1) asm volatile("s_waitcnt vmcnt(8)" ::: "memory");
            __builtin_amdgcn_s_barrier();
            asm volatile("s_waitcnt lgkmcnt(0)" ::: "memory");
            __builtin_amdgcn_sched_barrier(0);
            __builtin_amdgcn_s_setprio(1);
            #pragma unroll
            for (int i = 0; i < 4; i++)
                #pragma unroll
                for (int j = 0; j < 4; j++)
                    acc[mh * 4 + i][j] = __builtin_amdgcn_mfma_f32_16x16x32_bf16(
                        af[i], bfr[j], acc[mh * 4 + i][j], 0, 0, 0);
            __builtin_amdgcn_s_setprio(0);
            __builtin_amdgcn_s_barrier();
            __builtin_amdgcn_sched_barrier(0);
        }
    }
    asm volatile("s_waitcnt vmcnt(0)" ::: "memory");

    #pragma unroll
    for (int i = 0; i < 8; i++) {
        #pragma unroll
        for (int j = 0; j < 4; j++) {
            const int gn = n0 + wn * 64 + j * 16 + mr;
            const float cbv = bias[gn];
            #pragma unroll
            for (int r = 0; r < 4; r++) {
                const int gm = m0 + wm * 128 + i * 16 + q * 4 + r;
                C[(long)gm * 1024 + gn] = f2bf(acc[i][j][r] + cbv);
            }
        }
    }
}

// ---------------- forward norm over L (masked); wsum = S/(S+eps) ----------------
__global__ void k_fwnorm(const float* __restrict__ z, const int* __restrict__ mask,
                         unsigned short* __restrict__ a_fw, unsigned short* __restrict__ b_fw,
                         float* __restrict__ wsum_a, float* __restrict__ wsum_b)
{
    const int be = blockIdx.x;
    const int b = be >> 6;
    const float* zr = z + (long)be * L_SZ;
    const int* mr = mask + (long)b * L_SZ;
    const int tid = threadIdx.x;
    float sa = 0.f, sb = 0.f;
    for (int l = tid; l < L_SZ; l += 256) {
        float v = zr[l];
        if (mr[l] != 0) { sa += fmaxf(v, 0.f); sb += fmaxf(-v, 0.f); }
    }
    #pragma unroll
    for (int o = 32; o > 0; o >>= 1) { sa += __shfl_down(sa, o); sb += __shfl_down(sb, o); }
    __shared__ float red[8];
    int wave = tid >> 6, lane = tid & 63;
    if (lane == 0) { red[wave] = sa; red[4 + wave] = sb; }
    __syncthreads();
    float ta = red[0] + red[1] + red[2] + red[3];
    float tb = red[4] + red[5] + red[6] + red[7];
    float ia = 1.f / (ta + 1e-9f), ib = 1.f / (tb + 1e-9f);
    if (tid == 0) { wsum_a[be] = ta * ia; wsum_b[be] = tb * ib; }
    for (int l = tid; l < L_SZ; l += 256) {
        float v = zr[l];
        float m = (mr[l] != 0) ? 1.f : 0.f;
        a_fw[(long)be * L_SZ + l] = f2bf(fmaxf(v, 0.f) * m * ia);
        b_fw[(long)be * L_SZ + l] = f2bf(fmaxf(-v, 0.f) * m * ib);
    }
}

// ---------------- final: out = sig(sel)*(aw@clsA) + (1-sig)*(bw@clsB) via MFMA ----------------
__launch_bounds__(256)
__global__ void k_final_mfma(const unsigned short* __restrict__ aw,
                             const unsigned short* __restrict__ bw,
                             const unsigned short* __restrict__ caHi,
                             const unsigned short* __restrict__ caLo,
                             const unsigned short* __restrict__ cbHi,
                             const unsigned short* __restrict__ cbLo,
                             const unsigned short* __restrict__ selbf,   // bf16 logits
                             float* __restrict__ out)
{
    __shared__ __align__(16) unsigned short Aa[64 * 72];
    __shared__ __align__(16) unsigned short Ab[64 * 72];
    __shared__ __align__(16) unsigned short BaH[64 * 72];
    __shared__ __align__(16) unsigned short BaL[64 * 72];
    __shared__ __align__(16) unsigned short BbH[64 * 72];
    __shared__ __align__(16) unsigned short BbL[64 * 72];
    const int bz = blockIdx.z;
    const int l0 = blockIdx.y * 64, d0 = blockIdx.x * 64;
    const int tid = threadIdx.x;
    const int wave = tid >> 6, lane = tid & 63;
    const int q = lane >> 4, mr = lane & 15;

    const unsigned short* awb = aw + ((long)bz * L_SZ + l0) * NUM_EXP;
    const unsigned short* bwb = bw + ((long)bz * L_SZ + l0) * NUM_EXP;
    const long cbase = ((long)bz * D_MODEL + d0) * NUM_EXP;

    #pragma unroll
    for (int c = 0; c < 2; c++) {
        int idx = c * 256 + tid;
        int row = idx >> 3, kc = (idx & 7) * 8;
        int lw = row * 72 + kc;
        long ga = (long)row * NUM_EXP + kc;
        *(ushort8*)&Aa[lw]  = *(const ushort8*)(awb + ga);
        *(ushort8*)&Ab[lw]  = *(const ushort8*)(bwb + ga);
        *(ushort8*)&BaH[lw] = *(const ushort8*)(caHi + cbase + ga);
        *(ushort8*)&BaL[lw] = *(const ushort8*)(caLo + cbase + ga);
        *(ushort8*)&BbH[lw] = *(const ushort8*)(cbHi + cbase + ga);
        *(ushort8*)&BbL[lw] = *(const ushort8*)(cbLo + cbase + ga);
    }
    __syncthreads();

    floatx4 accA[4], accB[4];
    floatx4 z4 = {0.f, 0.f, 0.f, 0.f};
    #pragma unroll
    for (int j = 0; j < 4; j++) { accA[j] = z4; accB[j] = z4; }

    #pragma unroll
    for (int ks = 0; ks < 2; ks++) {
        int ko = ks * 32 + q * 8;
        bf16x8 fa = *(const bf16x8*)&Aa[(wave * 16 + mr) * 72 + ko];
        bf16x8 fb = *(const bf16x8*)&Ab[(wave * 16 + mr) * 72 + ko];
        #pragma unroll
        for (int j = 0; j < 4; j++) {
            int bo = (j * 16 + mr) * 72 + ko;
            accA[j] = __builtin_amdgcn_mfma_f32_16x16x32_bf16(fa, *(const bf16x8*)&BaH[bo], accA[j], 0, 0, 0);
            accA[j] = __builtin_amdgcn_mfma_f32_16x16x32_bf16(fa, *(const bf16x8*)&BaL[bo], accA[j], 0, 0, 0);
            accB[j] = __builtin_amdgcn_mfma_f32_16x16x32_bf16(fb, *(const bf16x8*)&BbH[bo], accB[j], 0, 0, 0);
            accB[j] = __builtin_amdgcn_mfma_f32_16x16x32_bf16(fb, *(const bf16x8*)&BbL[bo], accB[j], 0, 0, 0);
        }
    }

    #pragma unroll
    for (int j = 0; j < 4; j++) {
        #pragma unroll
        for (int r = 0; r < 4; r++) {
            int gl = l0 + wave * 16 + q * 4 + r;
            int gd = d0 + j * 16 + mr;
            long o = ((long)bz * L_SZ + gl) * D_MODEL + gd;
            float s = 1.f / (1.f + __expf(-bf2f(selbf[o])));
            out[o] = s * accA[j][r] + (1.f - s) * accB[j][r];
        }
    }
}

extern "C" void kernel_launch(void* const* d_in, const int* in_sizes, int n_in,
                              void* d_out, int out_size, void* d_ws, size_t ws_size,
                              hipStream_t stream)
{
    const float* x     = (const float*)d_in[0];
    const int*   nidx  = (const int*)d_in[1];
    const int*   mask  = (const int*)d_in[2];
    const float* q_emb = (const float*)d_in[3];
    const float* b_emb = (const float*)d_in[4];
    const float* Wk    = (const float*)d_in[5];
    const float* bk    = (const float*)d_in[6];
    const float* Wa    = (const float*)d_in[7];
    const float* ba    = (const float*)d_in[8];
    const float* Wb    = (const float*)d_in[9];
    const float* bb    = (const float*)d_in[10];
    const float* Ws    = (const float*)d_in[11];
    const float* bs    = (const float*)d_in[12];
    float* out = (float*)d_out;

    constexpr long BLD = (long)B_SZ * L_SZ * D_MODEL;
    constexpr long BEL = (long)B_SZ * NUM_EXP * L_SZ;
    constexpr long BED = (long)B_SZ * NUM_EXP * D_MODEL;
    constexpr long DD  = (long)D_MODEL * D_MODEL;

    char* w = (char*)d_ws;
    size_t off = 0;
    auto carve = [&](size_t bytes) { char* p = w + off; off += (bytes + 255) & ~(size_t)255; return p; };
    unsigned short* x_bf   = (unsigned short*)carve(BLD * 2);
    unsigned short* x_bfT  = (unsigned short*)carve(BLD * 2);  // later reused as sel logits
    unsigned short* wkT_bf = (unsigned short*)carve(DD * 2);
    unsigned short* wa_bf  = (unsigned short*)carve(DD * 2);
    unsigned short* wb_bf  = (unsigned short*)carve(DD * 2);
    unsigned short* ws_bf  = (unsigned short*)carve(DD * 2);
    unsigned short* qexp   = (unsigned short*)carve(BED * 2);
    float*          bias_e = (float*)carve(BED * 4);
    float*          qbk    = (float*)carve(B_SZ * NUM_EXP * 4);
    unsigned short* qk     = (unsigned short*)carve(BED * 2);
    float*          z      = (float*)carve(BEL * 4);
    unsigned short* a_fw   = (unsigned short*)carve(BEL * 2);
    unsigned short* b_fw   = (unsigned short*)carve(BEL * 2);
    float*          wsum_a = (float*)carve(B_SZ * NUM_EXP * 4);
    float*          wsum_b = (float*)carve(B_SZ * NUM_EXP * 4);
    unsigned short* a_bw   = (unsigned short*)carve(BEL * 2);
    unsigned short* b_bw   = (unsigned short*)carve(BEL * 2);
    unsigned short* fwx_a  = (unsigned short*)carve(BED * 2);
    unsigned short* fwx_b  = (unsigned short*)carve(BED * 2);
    unsigned short* caHi   = (unsigned short*)carve(BED * 2);
    unsigned short* caLo   = (unsigned short*)carve(BED * 2);
    unsigned short* cbHi   = (unsigned short*)carve(BED * 2);
    unsigned short* cbLo   = (unsigned short*)carve(BED * 2);
    if (ws_size < off) return;
    unsigned short* selbf = x_bfT;  // x_bfT dead after fw2 GEMM; sel GEMM runs after it

    // 1. conversions / transposes / gather
    k_convx<<<dim3(16, 32, B_SZ), 256, 0, stream>>>(x, x_bf, x_bfT);
    k_prep<<<2816, 256, 0, stream>>>(Wk, Wa, Wb, Ws, nidx, q_emb, b_emb, bk,
                                     wkT_bf, wa_bf, wb_bf, ws_bf, qexp, bias_e, qbk);

    // 2. qk[e,n] = sum_d qexp[e,d] * WkT[n,d]  (bf16 out; K-split x2)
    k_gemm_qk64<<<dim3(16, 1, B_SZ), 512, 0, stream>>>(qexp, wkT_bf, qk);

    // 3. z = (qk@x^T + qbk)/32 (f32) + fused bw-norm -> a_bw/b_bw
    k_gemm_z<<<dim3(32, 1, B_SZ), 512, 0, stream>>>(qk, x_bf, qbk, z, a_bw, b_bw);

    // 4. forward norm (masked, over L)
    k_fwnorm<<<B_SZ * NUM_EXP, 256, 0, stream>>>(z, mask, a_fw, b_fw, wsum_a, wsum_b);

    // 5. fwx_{a,b}[e,c] = sum_l fw[e,l]·xT[c,l]  (fused, shared B; K-split x2)
    k_gemm_fw2<<<dim3(16, 1, B_SZ), 512, 0, stream>>>(a_fw, b_fw, x_bfT, fwx_a, fwx_b);

    // 6. sel logits -> selbf (aliases x_bfT; runs AFTER fw2). 512 blocks = 128m x 4n.
    k_gemm_sel<<<512, 512, 0, stream>>>(x_bf, ws_bf, bs, selbf);

    // 7. cls (both sides fused, K-split x2), transposed split store
    k_gemm_cls64<<<dim3(16, 1, 32), 512, 0, stream>>>(fwx_a, fwx_b, wa_bf, wb_bf, ba, bb,
        wsum_a, wsum_b, bias_e, caHi, caLo, cbHi, cbLo);

    // 8. final blend
    k_final_mfma<<<dim3(16, 32, B_SZ), 256, 0, stream>>>(a_bw, b_bw, caHi, caLo, cbHi, cbLo, selbf, out);
}